// Round 1
// baseline (577.670 us; speedup 1.0000x reference)
//
#include <hip/hip_runtime.h>

#define DIM 128

// ---------------------------------------------------------------------------
// P[n,128] = X[n,128] @ W[128,128]   (W row-major, 128x128 sub-block of W_a)
// block = 128 threads, 8 rows per block; X rows staged in LDS (broadcast reads)
// ---------------------------------------------------------------------------
__global__ void proj_kernel(const float* __restrict__ X, const float* __restrict__ W,
                            float* __restrict__ P, int n) {
    __shared__ float xs[8][DIM];
    const int t = threadIdx.x;             // 0..127 = output column
    const int row0 = blockIdx.x * 8;
    #pragma unroll
    for (int e = 0; e < 8; ++e) {
        int row = row0 + e;
        xs[e][t] = (row < n) ? X[(size_t)row * DIM + t] : 0.0f;
    }
    __syncthreads();
    float acc[8] = {0.f,0.f,0.f,0.f,0.f,0.f,0.f,0.f};
    #pragma unroll 4
    for (int k = 0; k < DIM; ++k) {
        float wv = W[k * DIM + t];         // coalesced row of W across the wave
        #pragma unroll
        for (int e = 0; e < 8; ++e) acc[e] += xs[e][k] * wv;
    }
    #pragma unroll
    for (int e = 0; e < 8; ++e) {
        int row = row0 + e;
        if (row < n) P[(size_t)row * DIM + t] = acc[e];
    }
}

// ---------------------------------------------------------------------------
// q[i] = P[i,:] . Wa2      one wave (64 lanes) per row, 2 elems/lane
// ---------------------------------------------------------------------------
__global__ void rowdot_kernel(const float* __restrict__ P, const float* __restrict__ Wa2,
                              float* __restrict__ q, int n) {
    const int wid  = (int)((blockIdx.x * (size_t)blockDim.x + threadIdx.x) >> 6);
    const int lane = threadIdx.x & 63;
    if (wid >= n) return;
    const float* row = P + (size_t)wid * DIM;
    float v = row[lane] * Wa2[lane] + row[64 + lane] * Wa2[64 + lane];
    #pragma unroll
    for (int o = 32; o > 0; o >>= 1) v += __shfl_down(v, o);
    if (lane == 0) q[wid] = v;
}

// qc = b_a . Wa2 + b_a2   (single tiny block)
__global__ void qc_kernel(const float* __restrict__ b_a, const float* __restrict__ Wa2,
                          const float* __restrict__ b_a2, float* __restrict__ qc) {
    const int t = threadIdx.x;             // 128 threads
    float v = b_a[t] * Wa2[t];
    __shared__ float sred[2];
    #pragma unroll
    for (int o = 32; o > 0; o >>= 1) v += __shfl_down(v, o);
    if ((t & 63) == 0) sred[t >> 6] = v;
    __syncthreads();
    if (t == 0) qc[0] = sred[0] + sred[1] + b_a2[0];
}

// ---------------------------------------------------------------------------
// per-edge: w = exp(leaky_relu(q1[s]+q2[r]+q3[d]+qc));  denom[s] += w
// ---------------------------------------------------------------------------
__global__ void edge_w_kernel(const int* __restrict__ T, const float* __restrict__ q1,
                              const float* __restrict__ q2, const float* __restrict__ q3,
                              const float* __restrict__ qc, float* __restrict__ w,
                              float* __restrict__ denom, int E) {
    const int e = blockIdx.x * blockDim.x + threadIdx.x;
    if (e >= E) return;
    const int s = T[e], r = T[E + e], d = T[2 * E + e];
    float b = q1[s] + q2[r] + q3[d] + qc[0];
    b = (b > 0.0f) ? b : 0.01f * b;        // leaky_relu slope 0.01
    const float wv = __expf(b);
    w[e] = wv;
    atomicAdd(&denom[s], wv);
}

// ---------------------------------------------------------------------------
// acc[s,:] += w[e] * (P2[r,:] + P3[d,:])   one wave per edge, float2 per lane
// ---------------------------------------------------------------------------
__global__ void edge_acc_kernel(const int* __restrict__ T, const float* __restrict__ w,
                                const float* __restrict__ P2, const float* __restrict__ P3,
                                float* __restrict__ acc, int E) {
    const int e = (blockIdx.x << 2) + (threadIdx.x >> 6);   // 4 waves / block
    if (e >= E) return;
    const int lane = threadIdx.x & 63;
    const int s = T[e], r = T[E + e], d = T[2 * E + e];
    const float wv = w[e];
    const int c0 = lane << 1;
    const float2 p2 = *(const float2*)(P2 + (size_t)r * DIM + c0);
    const float2 p3 = *(const float2*)(P3 + (size_t)d * DIM + c0);
    atomicAdd(acc + (size_t)s * DIM + c0,     wv * (p2.x + p3.x));
    atomicAdd(acc + (size_t)s * DIM + c0 + 1, wv * (p2.y + p3.y));
}

// ---------------------------------------------------------------------------
// out = elu(P1 + b_a + acc/denom)      in-place on d_out (acc lives there)
// ---------------------------------------------------------------------------
__global__ void finalize_kernel(const float* __restrict__ P1, const float* __restrict__ b_a,
                                const float* __restrict__ denom, float* __restrict__ out,
                                int total) {
    const int idx = blockIdx.x * blockDim.x + threadIdx.x;
    if (idx >= total) return;
    const int i = idx >> 7, j = idx & 127;
    const float v = P1[idx] + b_a[j] + out[idx] / denom[i];
    out[idx] = (v > 0.0f) ? v : (__expf(v) - 1.0f);
}

extern "C" void kernel_launch(void* const* d_in, const int* in_sizes, int n_in,
                              void* d_out, int out_size, void* d_ws, size_t ws_size,
                              hipStream_t stream) {
    const int*   T    = (const int*)d_in[0];
    const float* ent  = (const float*)d_in[1];
    const float* rel  = (const float*)d_in[2];
    const float* W_a  = (const float*)d_in[4];
    const float* b_a  = (const float*)d_in[5];
    const float* W_a2 = (const float*)d_in[6];
    const float* b_a2 = (const float*)d_in[7];
    float* out = (float*)d_out;

    const int E  = in_sizes[0] / 3;
    const int NE = in_sizes[1] / DIM;
    const int NR = in_sizes[2] / DIM;

    float* ws = (float*)d_ws;
    size_t off = 0;
    float* P1 = ws + off; off += (size_t)NE * DIM;
    float* P3 = ws + off; off += (size_t)NE * DIM;
    float* P2 = ws + off; off += (size_t)NR * DIM;
    float* q1 = ws + off; off += NE;
    float* q3 = ws + off; off += NE;
    float* q2 = ws + off; off += NR;
    float* qc = ws + off; off += 64;
    float* den = ws + off; off += NE;
    float* w  = ws + off; off += E;

    // zero accumulators (harness does not re-poison between replays)
    hipMemsetAsync(den, 0, (size_t)NE * sizeof(float), stream);
    hipMemsetAsync(d_out, 0, (size_t)out_size * sizeof(float), stream);

    // projections: P1 = ent@W_a[0:128], P3 = ent@W_a[256:384], P2 = rel@W_a[128:256]
    proj_kernel<<<(NE + 7) / 8, 128, 0, stream>>>(ent, W_a,              P1, NE);
    proj_kernel<<<(NE + 7) / 8, 128, 0, stream>>>(ent, W_a + 256 * DIM, P3, NE);
    proj_kernel<<<(NR + 7) / 8, 128, 0, stream>>>(rel, W_a + 128 * DIM, P2, NR);

    // q vectors
    rowdot_kernel<<<(NE + 3) / 4, 256, 0, stream>>>(P1, W_a2, q1, NE);
    rowdot_kernel<<<(NE + 3) / 4, 256, 0, stream>>>(P3, W_a2, q3, NE);
    rowdot_kernel<<<(NR + 3) / 4, 256, 0, stream>>>(P2, W_a2, q2, NR);
    qc_kernel<<<1, 128, 0, stream>>>(b_a, W_a2, b_a2, qc);

    // per-edge weight + denominator
    edge_w_kernel<<<(E + 255) / 256, 256, 0, stream>>>(T, q1, q2, q3, qc, w, den, E);

    // weighted accumulation into d_out
    edge_acc_kernel<<<(E + 3) / 4, 256, 0, stream>>>(T, w, P2, P3, out, E);

    // finalize: elu(P1 + b_a + acc/denom)
    finalize_kernel<<<(NE * DIM + 255) / 256, 256, 0, stream>>>(P1, b_a, den, out, NE * DIM);
}

// Round 2
// 343.057 us; speedup vs baseline: 1.6839x; 1.6839x over previous
//
#include <hip/hip_runtime.h>

#define DIM 128

// ---------------------------------------------------------------------------
// P[n,128] = X[n,128] @ W[128,128] (+ optional bias row)
// block = 128 threads (t = output column), 8 rows/block staged in LDS
// ---------------------------------------------------------------------------
__global__ void proj_kernel(const float* __restrict__ X, const float* __restrict__ W,
                            const float* __restrict__ bias, float* __restrict__ P, int n) {
    __shared__ float xs[8][DIM];
    const int t = threadIdx.x;
    const int row0 = blockIdx.x * 8;
    #pragma unroll
    for (int e = 0; e < 8; ++e) {
        int row = row0 + e;
        xs[e][t] = (row < n) ? X[(size_t)row * DIM + t] : 0.0f;
    }
    __syncthreads();
    float acc[8] = {0.f,0.f,0.f,0.f,0.f,0.f,0.f,0.f};
    #pragma unroll 4
    for (int k = 0; k < DIM; ++k) {
        float wv = W[k * DIM + t];
        #pragma unroll
        for (int e = 0; e < 8; ++e) acc[e] += xs[e][k] * wv;
    }
    const float bv = bias ? bias[t] : 0.0f;
    #pragma unroll
    for (int e = 0; e < 8; ++e) {
        int row = row0 + e;
        if (row < n) P[(size_t)row * DIM + t] = acc[e] + bv;
    }
}

// ---------------------------------------------------------------------------
// q[i] = P[i,:] . Wa2      one wave per row, 2 elems/lane
// ---------------------------------------------------------------------------
__global__ void rowdot_kernel(const float* __restrict__ P, const float* __restrict__ Wa2,
                              float* __restrict__ q, int n) {
    const int wid  = (int)((blockIdx.x * (size_t)blockDim.x + threadIdx.x) >> 6);
    const int lane = threadIdx.x & 63;
    if (wid >= n) return;
    const float* row = P + (size_t)wid * DIM;
    float v = row[lane] * Wa2[lane] + row[64 + lane] * Wa2[64 + lane];
    #pragma unroll
    for (int o = 32; o > 0; o >>= 1) v += __shfl_down(v, o);
    if (lane == 0) q[wid] = v;
}

// ---------------------------------------------------------------------------
// per-edge: w = exp(leaky_relu(q1[s]+q2[r]+q3[d]+b_a2)); counts[s]++
// ---------------------------------------------------------------------------
__global__ void edge_w_kernel(const int* __restrict__ T, const float* __restrict__ q1,
                              const float* __restrict__ q2, const float* __restrict__ q3,
                              const float* __restrict__ b_a2, float* __restrict__ w,
                              int* __restrict__ counts, int E) {
    const int e = blockIdx.x * blockDim.x + threadIdx.x;
    if (e >= E) return;
    const int s = T[e], r = T[E + e], d = T[2 * E + e];
    float b = q1[s] + q2[r] + q3[d] + b_a2[0];
    b = (b > 0.0f) ? b : 0.01f * b;
    w[e] = __expf(b);
    atomicAdd(&counts[s], 1);
}

// ---------------------------------------------------------------------------
// single-block exclusive scan (1024 threads, ~49 elems/thread sequential)
// writes offsets[0..n-1] and a mutable copy in cursor[]; offsets[n]=E.
// ---------------------------------------------------------------------------
__device__ inline int wave_incl_scan(int v) {
    const int lane = threadIdx.x & 63;
    #pragma unroll
    for (int o = 1; o < 64; o <<= 1) {
        int u = __shfl_up(v, o);
        if (lane >= o) v += u;
    }
    return v;
}

__global__ void scan_kernel(const int* __restrict__ counts, int* __restrict__ offsets,
                            int* __restrict__ cursor, int n, int total) {
    const int t = threadIdx.x;                 // 1024 threads
    const int per = (n + 1023) / 1024;
    const int lo = t * per;
    const int hi = min(lo + per, n);
    int sum = 0;
    for (int i = lo; i < hi; ++i) sum += counts[i];
    int incl = wave_incl_scan(sum);
    __shared__ int wsum[16], wpre[16];
    const int wid = t >> 6, lane = t & 63;
    if (lane == 63) wsum[wid] = incl;
    __syncthreads();
    if (t < 16) {
        int v = wsum[t];
        #pragma unroll
        for (int o = 1; o < 16; o <<= 1) {
            int u = __shfl_up(v, o);
            if (t >= o) v += u;
        }
        wpre[t] = v - wsum[t];                 // exclusive wave prefix
    }
    __syncthreads();
    int run = incl - sum + wpre[wid];
    for (int i = lo; i < hi; ++i) {
        int c = counts[i];
        offsets[i] = run;
        cursor[i]  = run;
        run += c;
    }
    if (t == 0) offsets[n] = total;
}

// ---------------------------------------------------------------------------
// scatter edges into source-grouped order: (rel, dst, w) triples
// ---------------------------------------------------------------------------
__global__ void scatter_kernel(const int* __restrict__ T, const float* __restrict__ w,
                               int* __restrict__ cursor, int* __restrict__ rs,
                               int* __restrict__ ds, float* __restrict__ wsrt, int E) {
    const int e = blockIdx.x * blockDim.x + threadIdx.x;
    if (e >= E) return;
    const int s = T[e];
    const int pos = atomicAdd(&cursor[s], 1);
    rs[pos]   = T[E + e];
    ds[pos]   = T[2 * E + e];
    wsrt[pos] = w[e];
}

// ---------------------------------------------------------------------------
// one wave per node: out[s,:] = elu(P1b[s,:] + sum_e w*(P2[r]+P3[d]) / sum_e w)
// P1b (= P1 + b_a) lives in `out` already; read-then-overwrite per element.
// ---------------------------------------------------------------------------
__global__ void gather_kernel(const int* __restrict__ offsets, const int* __restrict__ rs,
                              const int* __restrict__ ds, const float* __restrict__ wsrt,
                              const float* __restrict__ P2, const float* __restrict__ P3,
                              float* __restrict__ out, int n) {
    const int node = (blockIdx.x << 2) + (threadIdx.x >> 6);   // 4 waves/block
    if (node >= n) return;
    const int lane = threadIdx.x & 63;
    const int lo = offsets[node], hi = offsets[node + 1];
    const int c0 = lane << 1;
    float ax = 0.f, ay = 0.f, wsum = 0.f;
    for (int i = lo; i < hi; ++i) {
        const int r = rs[i], d = ds[i];
        const float wv = wsrt[i];
        const float2 p2 = *(const float2*)(P2 + (size_t)r * DIM + c0);
        const float2 p3 = *(const float2*)(P3 + (size_t)d * DIM + c0);
        ax += wv * (p2.x + p3.x);
        ay += wv * (p2.y + p3.y);
        wsum += wv;
    }
    const float inv = 1.0f / wsum;             // every node has >=1 edge by construction
    const size_t o = (size_t)node * DIM + c0;
    const float v0 = out[o]     + ax * inv;
    const float v1 = out[o + 1] + ay * inv;
    out[o]     = (v0 > 0.0f) ? v0 : (__expf(v0) - 1.0f);
    out[o + 1] = (v1 > 0.0f) ? v1 : (__expf(v1) - 1.0f);
}

extern "C" void kernel_launch(void* const* d_in, const int* in_sizes, int n_in,
                              void* d_out, int out_size, void* d_ws, size_t ws_size,
                              hipStream_t stream) {
    const int*   T    = (const int*)d_in[0];
    const float* ent  = (const float*)d_in[1];
    const float* rel  = (const float*)d_in[2];
    const float* W_a  = (const float*)d_in[4];
    const float* b_a  = (const float*)d_in[5];
    const float* W_a2 = (const float*)d_in[6];
    const float* b_a2 = (const float*)d_in[7];
    float* out = (float*)d_out;

    const int E  = in_sizes[0] / 3;
    const int NE = in_sizes[1] / DIM;
    const int NR = in_sizes[2] / DIM;

    float* ws = (float*)d_ws;
    size_t off = 0;
    float* P3   = ws + off; off += (size_t)NE * DIM;
    float* P2   = ws + off; off += (size_t)NR * DIM;
    float* q1   = ws + off; off += NE;
    float* q3   = ws + off; off += NE;
    float* q2   = ws + off; off += NR + 64;
    float* w    = ws + off; off += E;
    float* wsrt = ws + off; off += E;
    int* counts  = (int*)(ws + off); off += NE;
    int* offsets = (int*)(ws + off); off += NE + 64;
    int* cursor  = (int*)(ws + off); off += NE;
    int* rs      = (int*)(ws + off); off += E;
    int* dsi     = (int*)(ws + off); off += E;

    // zero the histogram (graph replays: must re-init every call)
    hipMemsetAsync(counts, 0, (size_t)NE * sizeof(int), stream);

    // projections: P1+b_a -> out (gather reads-then-overwrites it), P3, P2
    proj_kernel<<<(NE + 7) / 8, 128, 0, stream>>>(ent, W_a,             b_a,  out, NE);
    proj_kernel<<<(NE + 7) / 8, 128, 0, stream>>>(ent, W_a + 256 * DIM, NULL, P3, NE);
    proj_kernel<<<(NR + 7) / 8, 128, 0, stream>>>(rel, W_a + 128 * DIM, NULL, P2, NR);

    // q vectors (q1 from biased P1 -> b_a·Wa2 already included)
    rowdot_kernel<<<(NE + 3) / 4, 256, 0, stream>>>(out, W_a2, q1, NE);
    rowdot_kernel<<<(NE + 3) / 4, 256, 0, stream>>>(P3,  W_a2, q3, NE);
    rowdot_kernel<<<(NR + 3) / 4, 256, 0, stream>>>(P2,  W_a2, q2, NR);

    // per-edge weights + per-source histogram
    edge_w_kernel<<<(E + 255) / 256, 256, 0, stream>>>(T, q1, q2, q3, b_a2, w, counts, E);

    // CSR offsets
    scan_kernel<<<1, 1024, 0, stream>>>(counts, offsets, cursor, NE, E);

    // group edges by source
    scatter_kernel<<<(E + 255) / 256, 256, 0, stream>>>(T, w, cursor, rs, dsi, wsrt, E);

    // gather + normalize + elu (fused finalize)
    gather_kernel<<<(NE + 3) / 4, 256, 0, stream>>>(offsets, rs, dsi, wsrt, P2, P3, out, NE);
}

// Round 3
// 233.587 us; speedup vs baseline: 2.4730x; 1.4686x over previous
//
#include <hip/hip_runtime.h>

#define DIM 128

// ---------------------------------------------------------------------------
// P[n,128] = X[n,128] @ W[128,128] (+ optional bias row), fused q = P·Wa2
// block = 128 threads (t = output column), 8 rows/block staged in LDS
// ---------------------------------------------------------------------------
__global__ void proj_kernel(const float* __restrict__ X, const float* __restrict__ W,
                            const float* __restrict__ bias, const float* __restrict__ Wa2,
                            float* __restrict__ P, float* __restrict__ q, int n) {
    __shared__ float xs[8][DIM];
    __shared__ float sred[8][2];
    const int t = threadIdx.x;
    const int row0 = blockIdx.x * 8;
    #pragma unroll
    for (int e = 0; e < 8; ++e) {
        int row = row0 + e;
        xs[e][t] = (row < n) ? X[(size_t)row * DIM + t] : 0.0f;
    }
    __syncthreads();
    float acc[8] = {0.f,0.f,0.f,0.f,0.f,0.f,0.f,0.f};
    #pragma unroll 4
    for (int k = 0; k < DIM; ++k) {
        float wv = W[k * DIM + t];
        #pragma unroll
        for (int e = 0; e < 8; ++e) acc[e] += xs[e][k] * wv;
    }
    const float bv = bias ? bias[t] : 0.0f;
    const float wa2 = Wa2[t];
    const int wid = t >> 6, lane = t & 63;
    #pragma unroll
    for (int e = 0; e < 8; ++e) {
        acc[e] += bv;
        float v = acc[e] * wa2;
        #pragma unroll
        for (int o = 32; o > 0; o >>= 1) v += __shfl_down(v, o);
        if (lane == 0) sred[e][wid] = v;
    }
    __syncthreads();
    #pragma unroll
    for (int e = 0; e < 8; ++e) {
        int row = row0 + e;
        if (row < n) P[(size_t)row * DIM + t] = acc[e];
    }
    if (t < 8) {
        int row = row0 + t;
        if (row < n) q[row] = sred[t][0] + sred[t][1];
    }
}

// ---------------------------------------------------------------------------
// histogram: counts[src]++  (read src column only)
// ---------------------------------------------------------------------------
__global__ void hist_kernel(const int* __restrict__ T, int* __restrict__ counts, int E) {
    const int e = blockIdx.x * blockDim.x + threadIdx.x;
    if (e < E) atomicAdd(&counts[T[e]], 1);
}

// ---------------------------------------------------------------------------
// hierarchical scan: 1024 elems/block
// ---------------------------------------------------------------------------
__device__ inline int wave_incl_scan(int v) {
    const int lane = threadIdx.x & 63;
    #pragma unroll
    for (int o = 1; o < 64; o <<= 1) {
        int u = __shfl_up(v, o);
        if (lane >= o) v += u;
    }
    return v;
}

__global__ void scan_bsum_kernel(const int* __restrict__ counts, int* __restrict__ bsum, int n) {
    const int t = threadIdx.x;                 // 256
    const int base = blockIdx.x * 1024 + t * 4;
    int s = 0;
    #pragma unroll
    for (int j = 0; j < 4; ++j) if (base + j < n) s += counts[base + j];
    #pragma unroll
    for (int o = 32; o > 0; o >>= 1) s += __shfl_down(s, o);
    __shared__ int ws[4];
    if ((t & 63) == 0) ws[t >> 6] = s;
    __syncthreads();
    if (t == 0) bsum[blockIdx.x] = ws[0] + ws[1] + ws[2] + ws[3];
}

// single wave scans the (<=64) block sums -> exclusive block offsets
__global__ void scan_boff_kernel(const int* __restrict__ bsum, int* __restrict__ boff, int nb) {
    const int lane = threadIdx.x;              // 64
    int v = (lane < nb) ? bsum[lane] : 0;
    int incl = wave_incl_scan(v);
    if (lane < nb) boff[lane] = incl - v;
}

__global__ void scan_write_kernel(const int* __restrict__ counts, const int* __restrict__ boff,
                                  int* __restrict__ offsets, int* __restrict__ cursor,
                                  int n, int total) {
    const int t = threadIdx.x;                 // 256
    const int base = blockIdx.x * 1024 + t * 4;
    int c[4];
    int s = 0;
    #pragma unroll
    for (int j = 0; j < 4; ++j) {
        c[j] = (base + j < n) ? counts[base + j] : 0;
        s += c[j];
    }
    int incl = wave_incl_scan(s);
    __shared__ int wsum[4], wpre[4];
    const int wid = t >> 6, lane = t & 63;
    if (lane == 63) wsum[wid] = incl;
    __syncthreads();
    if (t == 0) {
        int run = 0;
        #pragma unroll
        for (int k = 0; k < 4; ++k) { wpre[k] = run; run += wsum[k]; }
    }
    __syncthreads();
    int run = incl - s + wpre[wid] + boff[blockIdx.x];
    #pragma unroll
    for (int j = 0; j < 4; ++j) {
        if (base + j < n) { offsets[base + j] = run; cursor[base + j] = run; run += c[j]; }
    }
    if (base == 0 && blockIdx.x == 0) offsets[n] = total;
}

// ---------------------------------------------------------------------------
// fused weight + scatter: w = exp(lrelu(q1[s]+q2[r]+q3[d]+b_a2));
// place (r, d, w) at cursor[s]++
// ---------------------------------------------------------------------------
__global__ void scatter_kernel(const int* __restrict__ T, const float* __restrict__ q1,
                               const float* __restrict__ q2, const float* __restrict__ q3,
                               const float* __restrict__ b_a2, int* __restrict__ cursor,
                               int* __restrict__ rs, int* __restrict__ ds,
                               float* __restrict__ wsrt, int E) {
    const int e = blockIdx.x * blockDim.x + threadIdx.x;
    if (e >= E) return;
    const int s = T[e], r = T[E + e], d = T[2 * E + e];
    float b = q1[s] + q2[r] + q3[d] + b_a2[0];
    b = (b > 0.0f) ? b : 0.01f * b;
    const int pos = atomicAdd(&cursor[s], 1);
    rs[pos]   = r;
    ds[pos]   = d;
    wsrt[pos] = __expf(b);
}

// ---------------------------------------------------------------------------
// one wave per node: out[s,:] = elu(P1b[s,:] + sum_e w*(P2[r]+P3[d]) / sum_e w)
// P1b (= P1 + b_a) lives in `out` already; read-then-overwrite per element.
// ---------------------------------------------------------------------------
__global__ void gather_kernel(const int* __restrict__ offsets, const int* __restrict__ rs,
                              const int* __restrict__ ds, const float* __restrict__ wsrt,
                              const float* __restrict__ P2, const float* __restrict__ P3,
                              float* __restrict__ out, int n) {
    const int node = (blockIdx.x << 2) + (threadIdx.x >> 6);   // 4 waves/block
    if (node >= n) return;
    const int lane = threadIdx.x & 63;
    const int lo = offsets[node], hi = offsets[node + 1];
    const int c0 = lane << 1;
    float ax = 0.f, ay = 0.f, wsum = 0.f;
    for (int i = lo; i < hi; ++i) {
        const int r = rs[i], d = ds[i];
        const float wv = wsrt[i];
        const float2 p2 = *(const float2*)(P2 + (size_t)r * DIM + c0);
        const float2 p3 = *(const float2*)(P3 + (size_t)d * DIM + c0);
        ax += wv * (p2.x + p3.x);
        ay += wv * (p2.y + p3.y);
        wsum += wv;
    }
    const float inv = 1.0f / wsum;
    const size_t o = (size_t)node * DIM + c0;
    const float v0 = out[o]     + ax * inv;
    const float v1 = out[o + 1] + ay * inv;
    out[o]     = (v0 > 0.0f) ? v0 : (__expf(v0) - 1.0f);
    out[o + 1] = (v1 > 0.0f) ? v1 : (__expf(v1) - 1.0f);
}

extern "C" void kernel_launch(void* const* d_in, const int* in_sizes, int n_in,
                              void* d_out, int out_size, void* d_ws, size_t ws_size,
                              hipStream_t stream) {
    const int*   T    = (const int*)d_in[0];
    const float* ent  = (const float*)d_in[1];
    const float* rel  = (const float*)d_in[2];
    const float* W_a  = (const float*)d_in[4];
    const float* b_a  = (const float*)d_in[5];
    const float* W_a2 = (const float*)d_in[6];
    const float* b_a2 = (const float*)d_in[7];
    float* out = (float*)d_out;

    const int E  = in_sizes[0] / 3;
    const int NE = in_sizes[1] / DIM;
    const int NR = in_sizes[2] / DIM;
    const int NB = (NE + 1023) / 1024;         // scan blocks (<=64 supported)

    float* ws = (float*)d_ws;
    size_t off = 0;
    float* P3   = ws + off; off += (size_t)NE * DIM;
    float* P2   = ws + off; off += (size_t)NR * DIM;
    float* q1   = ws + off; off += NE;
    float* q3   = ws + off; off += NE;
    float* q2   = ws + off; off += NR + 64;
    float* wsrt = ws + off; off += E;
    int* counts  = (int*)(ws + off); off += NE;
    int* offsets = (int*)(ws + off); off += NE + 64;
    int* cursor  = (int*)(ws + off); off += NE;
    int* bsum    = (int*)(ws + off); off += 64;
    int* boff    = (int*)(ws + off); off += 64;
    int* rs      = (int*)(ws + off); off += E;
    int* dsi     = (int*)(ws + off); off += E;

    // zero the histogram (graph replays: must re-init every call)
    hipMemsetAsync(counts, 0, (size_t)NE * sizeof(int), stream);

    // projections (+ fused q): P1+b_a -> out, P3, P2
    proj_kernel<<<(NE + 7) / 8, 128, 0, stream>>>(ent, W_a,             b_a,  W_a2, out, q1, NE);
    proj_kernel<<<(NE + 7) / 8, 128, 0, stream>>>(ent, W_a + 256 * DIM, NULL, W_a2, P3,  q3, NE);
    proj_kernel<<<(NR + 7) / 8, 128, 0, stream>>>(rel, W_a + 128 * DIM, NULL, W_a2, P2,  q2, NR);

    // per-source histogram
    hist_kernel<<<(E + 255) / 256, 256, 0, stream>>>(T, counts, E);

    // hierarchical CSR scan
    scan_bsum_kernel<<<NB, 256, 0, stream>>>(counts, bsum, NE);
    scan_boff_kernel<<<1, 64, 0, stream>>>(bsum, boff, NB);
    scan_write_kernel<<<NB, 256, 0, stream>>>(counts, boff, offsets, cursor, NE, E);

    // fused weight + scatter (group edges by source)
    scatter_kernel<<<(E + 255) / 256, 256, 0, stream>>>(T, q1, q2, q3, b_a2, cursor, rs, dsi, wsrt, E);

    // gather + normalize + elu (fused finalize)
    gather_kernel<<<(NE + 3) / 4, 256, 0, stream>>>(offsets, rs, dsi, wsrt, P2, P3, out, NE);
}

// Round 4
// 206.800 us; speedup vs baseline: 2.7934x; 1.1295x over previous
//
#include <hip/hip_runtime.h>

#define DIM 128

// ---- bf16 pack/unpack (RNE) ------------------------------------------------
__device__ inline unsigned pack_bf16(float lo, float hi) {
    unsigned a = __float_as_uint(lo), b = __float_as_uint(hi);
    a = (a + 0x8000u + ((a >> 16) & 1u)) >> 16;
    b = (b + 0x8000u + ((b >> 16) & 1u)) >> 16;
    return a | (b << 16);
}
__device__ inline float unpack_lo(unsigned v) { return __uint_as_float(v << 16); }
__device__ inline float unpack_hi(unsigned v) { return __uint_as_float(v & 0xFFFF0000u); }

// ---------------------------------------------------------------------------
// Fused dual projection over ent: P1 = ent@W1 + b_a -> out (fp32),
// P3 = ent@W3 -> P3h (packed bf16), q1 = P1·Wa2, q3 = P3·Wa2.
// block = 128 threads (t = output column), 8 rows/block staged in LDS.
// ---------------------------------------------------------------------------
__global__ void proj_dual_kernel(const float* __restrict__ X, const float* __restrict__ W1,
                                 const float* __restrict__ W3, const float* __restrict__ b_a,
                                 const float* __restrict__ Wa2, float* __restrict__ out,
                                 unsigned* __restrict__ P3h, float* __restrict__ q1,
                                 float* __restrict__ q3, int n) {
    __shared__ float xs[8][DIM];
    __shared__ float sred1[8][2], sred3[8][2];
    const int t = threadIdx.x;
    const int row0 = blockIdx.x * 8;
    #pragma unroll
    for (int e = 0; e < 8; ++e) {
        int row = row0 + e;
        xs[e][t] = (row < n) ? X[(size_t)row * DIM + t] : 0.0f;
    }
    __syncthreads();
    float a1[8] = {0,0,0,0,0,0,0,0};
    float a3[8] = {0,0,0,0,0,0,0,0};
    #pragma unroll 4
    for (int k = 0; k < DIM; ++k) {
        const float w1 = W1[k * DIM + t];
        const float w3 = W3[k * DIM + t];
        #pragma unroll
        for (int e = 0; e < 8; ++e) {
            a1[e] += xs[e][k] * w1;
            a3[e] += xs[e][k] * w3;
        }
    }
    const float bv = b_a[t];
    const float wa2 = Wa2[t];
    const int wid = t >> 6, lane = t & 63;
    #pragma unroll
    for (int e = 0; e < 8; ++e) {
        a1[e] += bv;
        float v1 = a1[e] * wa2;
        float v3 = a3[e] * wa2;
        #pragma unroll
        for (int o = 32; o > 0; o >>= 1) { v1 += __shfl_down(v1, o); v3 += __shfl_down(v3, o); }
        if (lane == 0) { sred1[e][wid] = v1; sred3[e][wid] = v3; }
    }
    __syncthreads();
    #pragma unroll
    for (int e = 0; e < 8; ++e) {
        int row = row0 + e;
        float hi = __shfl_down(a3[e], 1);
        if (row < n) {
            out[(size_t)row * DIM + t] = a1[e];
            if ((t & 1) == 0) P3h[(size_t)row * 64 + (t >> 1)] = pack_bf16(a3[e], hi);
        }
    }
    if (t < 8) {
        int row = row0 + t;
        if (row < n) { q1[row] = sred1[t][0] + sred1[t][1]; q3[row] = sred3[t][0] + sred3[t][1]; }
    }
}

// ---------------------------------------------------------------------------
// Single projection (rel): P2 = rel@W2 -> bf16 packed, q2 = P2·Wa2
// ---------------------------------------------------------------------------
__global__ void proj_rel_kernel(const float* __restrict__ X, const float* __restrict__ W,
                                const float* __restrict__ Wa2, unsigned* __restrict__ Ph,
                                float* __restrict__ q, int n) {
    __shared__ float xs[8][DIM];
    __shared__ float sred[8][2];
    const int t = threadIdx.x;
    const int row0 = blockIdx.x * 8;
    #pragma unroll
    for (int e = 0; e < 8; ++e) {
        int row = row0 + e;
        xs[e][t] = (row < n) ? X[(size_t)row * DIM + t] : 0.0f;
    }
    __syncthreads();
    float acc[8] = {0,0,0,0,0,0,0,0};
    #pragma unroll 4
    for (int k = 0; k < DIM; ++k) {
        const float wv = W[k * DIM + t];
        #pragma unroll
        for (int e = 0; e < 8; ++e) acc[e] += xs[e][k] * wv;
    }
    const float wa2 = Wa2[t];
    const int wid = t >> 6, lane = t & 63;
    #pragma unroll
    for (int e = 0; e < 8; ++e) {
        float v = acc[e] * wa2;
        #pragma unroll
        for (int o = 32; o > 0; o >>= 1) v += __shfl_down(v, o);
        if (lane == 0) sred[e][wid] = v;
    }
    __syncthreads();
    #pragma unroll
    for (int e = 0; e < 8; ++e) {
        int row = row0 + e;
        float hi = __shfl_down(acc[e], 1);
        if (row < n && (t & 1) == 0) Ph[(size_t)row * 64 + (t >> 1)] = pack_bf16(acc[e], hi);
    }
    if (t < 8) {
        int row = row0 + t;
        if (row < n) q[row] = sred[t][0] + sred[t][1];
    }
}

// ---------------------------------------------------------------------------
__global__ void hist_kernel(const int* __restrict__ T, int* __restrict__ counts, int E) {
    const int e = blockIdx.x * blockDim.x + threadIdx.x;
    if (e < E) atomicAdd(&counts[T[e]], 1);
}

// ---------------------------------------------------------------------------
__device__ inline int wave_incl_scan(int v) {
    const int lane = threadIdx.x & 63;
    #pragma unroll
    for (int o = 1; o < 64; o <<= 1) {
        int u = __shfl_up(v, o);
        if (lane >= o) v += u;
    }
    return v;
}

__global__ void scan_bsum_kernel(const int* __restrict__ counts, int* __restrict__ bsum, int n) {
    const int t = threadIdx.x;                 // 256
    const int base = blockIdx.x * 1024 + t * 4;
    int s = 0;
    #pragma unroll
    for (int j = 0; j < 4; ++j) if (base + j < n) s += counts[base + j];
    #pragma unroll
    for (int o = 32; o > 0; o >>= 1) s += __shfl_down(s, o);
    __shared__ int ws[4];
    if ((t & 63) == 0) ws[t >> 6] = s;
    __syncthreads();
    if (t == 0) bsum[blockIdx.x] = ws[0] + ws[1] + ws[2] + ws[3];
}

__global__ void scan_boff_kernel(const int* __restrict__ bsum, int* __restrict__ boff, int nb) {
    const int lane = threadIdx.x;              // 64
    int v = (lane < nb) ? bsum[lane] : 0;
    int incl = wave_incl_scan(v);
    if (lane < nb) boff[lane] = incl - v;
}

__global__ void scan_write_kernel(const int* __restrict__ counts, const int* __restrict__ boff,
                                  int* __restrict__ offsets, int* __restrict__ cursor,
                                  int n, int total) {
    const int t = threadIdx.x;                 // 256
    const int base = blockIdx.x * 1024 + t * 4;
    int c[4];
    int s = 0;
    #pragma unroll
    for (int j = 0; j < 4; ++j) {
        c[j] = (base + j < n) ? counts[base + j] : 0;
        s += c[j];
    }
    int incl = wave_incl_scan(s);
    __shared__ int wsum[4], wpre[4];
    const int wid = t >> 6, lane = t & 63;
    if (lane == 63) wsum[wid] = incl;
    __syncthreads();
    if (t == 0) {
        int run = 0;
        #pragma unroll
        for (int k = 0; k < 4; ++k) { wpre[k] = run; run += wsum[k]; }
    }
    __syncthreads();
    int run = incl - s + wpre[wid] + boff[blockIdx.x];
    #pragma unroll
    for (int j = 0; j < 4; ++j) {
        if (base + j < n) { offsets[base + j] = run; cursor[base + j] = run; run += c[j]; }
    }
    if (base == 0 && blockIdx.x == 0) offsets[n] = total;
}

// ---------------------------------------------------------------------------
// scatter (r, d) into source-grouped CSR order (8 B payload per edge)
// ---------------------------------------------------------------------------
__global__ void scatter_kernel(const int* __restrict__ T, int* __restrict__ cursor,
                               int2* __restrict__ rd, int E) {
    const int e = blockIdx.x * blockDim.x + threadIdx.x;
    if (e >= E) return;
    const int s = T[e];
    const int pos = atomicAdd(&cursor[s], 1);
    rd[pos] = make_int2(T[E + e], T[2 * E + e]);
}

// ---------------------------------------------------------------------------
// one wave per node: recompute w from q's, gather bf16 rows, normalize, elu.
// P1b (= P1 + b_a) lives in `out`; read-then-overwrite per element.
// ---------------------------------------------------------------------------
__global__ void gather_kernel(const int* __restrict__ offsets, const int2* __restrict__ rd,
                              const float* __restrict__ q1, const float* __restrict__ q2,
                              const float* __restrict__ q3, const float* __restrict__ b_a2,
                              const unsigned* __restrict__ P2h, const unsigned* __restrict__ P3h,
                              float* __restrict__ out, int n) {
    const int node = (blockIdx.x << 2) + (threadIdx.x >> 6);   // 4 waves/block
    if (node >= n) return;
    const int lane = threadIdx.x & 63;
    const int lo = offsets[node], hi = offsets[node + 1];
    const float qn = q1[node] + b_a2[0];
    float ax = 0.f, ay = 0.f, wsum = 0.f;
    for (int i = lo; i < hi; ++i) {
        const int2 e = rd[i];
        float b = qn + q2[e.x] + q3[e.y];
        b = (b > 0.0f) ? b : 0.01f * b;
        const float wv = __expf(b);
        const unsigned v2 = P2h[(size_t)e.x * 64 + lane];
        const unsigned v3 = P3h[(size_t)e.y * 64 + lane];
        ax += wv * (unpack_lo(v2) + unpack_lo(v3));
        ay += wv * (unpack_hi(v2) + unpack_hi(v3));
        wsum += wv;
    }
    const float inv = 1.0f / wsum;
    const size_t o = (size_t)node * DIM + (lane << 1);
    const float v0 = out[o]     + ax * inv;
    const float v1 = out[o + 1] + ay * inv;
    out[o]     = (v0 > 0.0f) ? v0 : (__expf(v0) - 1.0f);
    out[o + 1] = (v1 > 0.0f) ? v1 : (__expf(v1) - 1.0f);
}

extern "C" void kernel_launch(void* const* d_in, const int* in_sizes, int n_in,
                              void* d_out, int out_size, void* d_ws, size_t ws_size,
                              hipStream_t stream) {
    const int*   T    = (const int*)d_in[0];
    const float* ent  = (const float*)d_in[1];
    const float* rel  = (const float*)d_in[2];
    const float* W_a  = (const float*)d_in[4];
    const float* b_a  = (const float*)d_in[5];
    const float* W_a2 = (const float*)d_in[6];
    const float* b_a2 = (const float*)d_in[7];
    float* out = (float*)d_out;

    const int E  = in_sizes[0] / 3;
    const int NE = in_sizes[1] / DIM;
    const int NR = in_sizes[2] / DIM;
    const int NB = (NE + 1023) / 1024;         // scan blocks (<=64 supported)

    float* ws = (float*)d_ws;
    size_t off = 0;
    unsigned* P3h = (unsigned*)(ws + off); off += (size_t)NE * 64;
    unsigned* P2h = (unsigned*)(ws + off); off += (size_t)NR * 64;
    float* q1   = ws + off; off += NE;
    float* q3   = ws + off; off += NE;
    float* q2   = ws + off; off += NR + 64;
    int* counts  = (int*)(ws + off); off += NE;
    int* offsets = (int*)(ws + off); off += NE + 64;
    int* cursor  = (int*)(ws + off); off += NE;
    int* bsum    = (int*)(ws + off); off += 64;
    int* boff    = (int*)(ws + off); off += 64;
    int2* rd     = (int2*)(ws + off); off += (size_t)E * 2;

    // zero the histogram (graph replays: must re-init every call)
    hipMemsetAsync(counts, 0, (size_t)NE * sizeof(int), stream);

    // projections: P1+b_a -> out (fp32) & P3 -> bf16 (one ent pass); P2 -> bf16
    proj_dual_kernel<<<(NE + 7) / 8, 128, 0, stream>>>(ent, W_a, W_a + 256 * DIM, b_a, W_a2,
                                                       out, P3h, q1, q3, NE);
    proj_rel_kernel<<<(NR + 7) / 8, 128, 0, stream>>>(rel, W_a + 128 * DIM, W_a2, P2h, q2, NR);

    // per-source histogram
    hist_kernel<<<(E + 255) / 256, 256, 0, stream>>>(T, counts, E);

    // hierarchical CSR scan
    scan_bsum_kernel<<<NB, 256, 0, stream>>>(counts, bsum, NE);
    scan_boff_kernel<<<1, 64, 0, stream>>>(bsum, boff, NB);
    scan_write_kernel<<<NB, 256, 0, stream>>>(counts, boff, offsets, cursor, NE, E);

    // scatter edges into source-grouped order
    scatter_kernel<<<(E + 255) / 256, 256, 0, stream>>>(T, cursor, rd, E);

    // gather + softmax-normalize + elu (weights recomputed from q's)
    gather_kernel<<<(NE + 3) / 4, 256, 0, stream>>>(offsets, rd, q1, q2, q3, b_a2,
                                                    P2h, P3h, out, NE);
}

// Round 5
// 185.724 us; speedup vs baseline: 3.1104x; 1.1135x over previous
//
#include <hip/hip_runtime.h>

#define DIM 128

typedef __attribute__((ext_vector_type(8))) short bf16x8;
typedef __attribute__((ext_vector_type(4))) float f32x4;

// ---- bf16 helpers (RNE) ----------------------------------------------------
__device__ inline unsigned short to_bf16(float f) {
    unsigned u = __float_as_uint(f);
    u = (u + 0x7FFFu + ((u >> 16) & 1u)) >> 16;
    return (unsigned short)u;
}
__device__ inline unsigned pack_bf16(float lo, float hi) {
    return (unsigned)to_bf16(lo) | ((unsigned)to_bf16(hi) << 16);
}
__device__ inline float unpack_lo(unsigned v) { return __uint_as_float(v << 16); }
__device__ inline float unpack_hi(unsigned v) { return __uint_as_float(v & 0xFFFF0000u); }

// ---------------------------------------------------------------------------
// W prep: Wt[c][k] (bf16, c in 0..255) = W_a[k][c] for c<128 (W1 block),
//                                       = W_a[256+k][c-128] for c>=128 (W3 block)
// ---------------------------------------------------------------------------
__global__ void wprep_kernel(const float* __restrict__ W_a, unsigned short* __restrict__ Wt) {
    const int c = blockIdx.x;          // 0..255
    const int k = threadIdx.x;         // 0..127
    const int srow = (c < 128) ? k : (256 + k);
    const int scol = (c < 128) ? c : (c - 128);
    Wt[c * DIM + k] = to_bf16(W_a[srow * DIM + scol]);
}

// ---------------------------------------------------------------------------
// MFMA dual projection over ent rows (16 rows per wave, 4 waves/block):
//   P1 = ent@W1 + b_a -> out (fp32), P3 = ent@W3 -> P3h (packed bf16)
//   q1 = P1b·Wa2, q3 = P3·Wa2
// A frag: lane holds ent[row0+(l&15)][kk*32 + (l>>4)*8 + i]  (8 contig k)
// B frag: lane holds Wt[ct*16+(l&15)][kk*32 + (l>>4)*8 + i]  (same k map)
// C/D   : reg r -> row=(l>>4)*4+r, col=l&15   [HW-verified]
// ---------------------------------------------------------------------------
__global__ __launch_bounds__(256) void proj_mfma_kernel(
        const float* __restrict__ ent, const unsigned short* __restrict__ Wt,
        const float* __restrict__ b_a, const float* __restrict__ Wa2,
        float* __restrict__ out, unsigned* __restrict__ P3h,
        float* __restrict__ q1, float* __restrict__ q3, int n, int ntiles) {
    const int tile = blockIdx.x * 4 + (threadIdx.x >> 6);
    if (tile >= ntiles) return;
    const int lane = threadIdx.x & 63;
    const int g = lane >> 4;           // k-group / row-group
    const int m = lane & 15;           // A row within tile; C col within tile
    const int row0 = tile * 16;

    // ---- load + convert A fragments (reused across all 16 col-tiles)
    const int rowA = min(row0 + m, n - 1);
    const float* arow = ent + (size_t)rowA * DIM;
    bf16x8 afrag[4];
    #pragma unroll
    for (int kk = 0; kk < 4; ++kk) {
        const float4 u0 = *(const float4*)(arow + kk * 32 + g * 8);
        const float4 u1 = *(const float4*)(arow + kk * 32 + g * 8 + 4);
        bf16x8 a;
        a[0] = (short)to_bf16(u0.x); a[1] = (short)to_bf16(u0.y);
        a[2] = (short)to_bf16(u0.z); a[3] = (short)to_bf16(u0.w);
        a[4] = (short)to_bf16(u1.x); a[5] = (short)to_bf16(u1.y);
        a[6] = (short)to_bf16(u1.z); a[7] = (short)to_bf16(u1.w);
        afrag[kk] = a;
    }

    float qp1[4] = {0.f, 0.f, 0.f, 0.f};
    float qp3[4] = {0.f, 0.f, 0.f, 0.f};

    #pragma unroll
    for (int ct = 0; ct < 16; ++ct) {
        f32x4 acc = {0.f, 0.f, 0.f, 0.f};
        #pragma unroll
        for (int kk = 0; kk < 4; ++kk) {
            const bf16x8 b = *(const bf16x8*)(Wt + (ct * 16 + m) * DIM + kk * 32 + g * 8);
            acc = __builtin_amdgcn_mfma_f32_16x16x32_bf16(afrag[kk], b, acc, 0, 0, 0);
        }
        const int c = ct * 16 + m;     // 0..255 combined column
        if (ct < 8) {
            // W1 block: add bias, store fp32 to out, accumulate q1
            const float bias = b_a[c];
            const float wa2  = Wa2[c];
            #pragma unroll
            for (int r = 0; r < 4; ++r) {
                const int row = row0 + g * 4 + r;
                const float v = acc[r] + bias;
                if (row < n) out[(size_t)row * DIM + c] = v;
                qp1[r] += v * wa2;
            }
        } else {
            // W3 block: accumulate q3, pack bf16 pairs into P3h
            const int c3 = c - 128;    // 0..127
            const float wa2 = Wa2[c3];
            #pragma unroll
            for (int r = 0; r < 4; ++r) {
                const int row = row0 + g * 4 + r;
                const float v = acc[r];
                qp3[r] += v * wa2;
                const float partner = __shfl_xor(v, 1);
                if ((m & 1) == 0 && row < n)
                    P3h[(size_t)row * 64 + (c3 >> 1)] = pack_bf16(v, partner);
            }
        }
    }

    // ---- reduce q over the 16 lanes of each row-group and store
    #pragma unroll
    for (int r = 0; r < 4; ++r) {
        float v1 = qp1[r], v3 = qp3[r];
        #pragma unroll
        for (int o = 1; o < 16; o <<= 1) {
            v1 += __shfl_xor(v1, o);
            v3 += __shfl_xor(v3, o);
        }
        const int row = row0 + g * 4 + r;
        if (m == 0 && row < n) { q1[row] = v1; q3[row] = v3; }
    }
}

// ---------------------------------------------------------------------------
// Single projection (rel, 500 rows): P2 = rel@W2 -> bf16 packed, q2 = P2·Wa2
// ---------------------------------------------------------------------------
__global__ void proj_rel_kernel(const float* __restrict__ X, const float* __restrict__ W,
                                const float* __restrict__ Wa2, unsigned* __restrict__ Ph,
                                float* __restrict__ q, int n) {
    __shared__ float xs[8][DIM];
    __shared__ float sred[8][2];
    const int t = threadIdx.x;
    const int row0 = blockIdx.x * 8;
    #pragma unroll
    for (int e = 0; e < 8; ++e) {
        int row = row0 + e;
        xs[e][t] = (row < n) ? X[(size_t)row * DIM + t] : 0.0f;
    }
    __syncthreads();
    float acc[8] = {0,0,0,0,0,0,0,0};
    #pragma unroll 4
    for (int k = 0; k < DIM; ++k) {
        const float wv = W[k * DIM + t];
        #pragma unroll
        for (int e = 0; e < 8; ++e) acc[e] += xs[e][k] * wv;
    }
    const float wa2 = Wa2[t];
    const int wid = t >> 6, lane = t & 63;
    #pragma unroll
    for (int e = 0; e < 8; ++e) {
        float v = acc[e] * wa2;
        #pragma unroll
        for (int o = 32; o > 0; o >>= 1) v += __shfl_down(v, o);
        if (lane == 0) sred[e][wid] = v;
    }
    __syncthreads();
    #pragma unroll
    for (int e = 0; e < 8; ++e) {
        int row = row0 + e;
        float hi = __shfl_down(acc[e], 1);
        if (row < n && (t & 1) == 0) Ph[(size_t)row * 64 + (t >> 1)] = pack_bf16(acc[e], hi);
    }
    if (t < 8) {
        int row = row0 + t;
        if (row < n) q[row] = sred[t][0] + sred[t][1];
    }
}

// ---------------------------------------------------------------------------
__global__ void hist_kernel(const int* __restrict__ T, int* __restrict__ counts, int E) {
    const int e = blockIdx.x * blockDim.x + threadIdx.x;
    if (e < E) atomicAdd(&counts[T[e]], 1);
}

// ---------------------------------------------------------------------------
__device__ inline int wave_incl_scan(int v) {
    const int lane = threadIdx.x & 63;
    #pragma unroll
    for (int o = 1; o < 64; o <<= 1) {
        int u = __shfl_up(v, o);
        if (lane >= o) v += u;
    }
    return v;
}

__global__ void scan_bsum_kernel(const int* __restrict__ counts, int* __restrict__ bsum, int n) {
    const int t = threadIdx.x;                 // 256
    const int base = blockIdx.x * 1024 + t * 4;
    int s = 0;
    #pragma unroll
    for (int j = 0; j < 4; ++j) if (base + j < n) s += counts[base + j];
    #pragma unroll
    for (int o = 32; o > 0; o >>= 1) s += __shfl_down(s, o);
    __shared__ int ws[4];
    if ((t & 63) == 0) ws[t >> 6] = s;
    __syncthreads();
    if (t == 0) bsum[blockIdx.x] = ws[0] + ws[1] + ws[2] + ws[3];
}

__global__ void scan_boff_kernel(const int* __restrict__ bsum, int* __restrict__ boff, int nb) {
    const int lane = threadIdx.x;              // 64
    int v = (lane < nb) ? bsum[lane] : 0;
    int incl = wave_incl_scan(v);
    if (lane < nb) boff[lane] = incl - v;
}

__global__ void scan_write_kernel(const int* __restrict__ counts, const int* __restrict__ boff,
                                  int* __restrict__ offsets, int* __restrict__ cursor,
                                  int n, int total) {
    const int t = threadIdx.x;                 // 256
    const int base = blockIdx.x * 1024 + t * 4;
    int c[4];
    int s = 0;
    #pragma unroll
    for (int j = 0; j < 4; ++j) {
        c[j] = (base + j < n) ? counts[base + j] : 0;
        s += c[j];
    }
    int incl = wave_incl_scan(s);
    __shared__ int wsum[4], wpre[4];
    const int wid = t >> 6, lane = t & 63;
    if (lane == 63) wsum[wid] = incl;
    __syncthreads();
    if (t == 0) {
        int run = 0;
        #pragma unroll
        for (int k = 0; k < 4; ++k) { wpre[k] = run; run += wsum[k]; }
    }
    __syncthreads();
    int run = incl - s + wpre[wid] + boff[blockIdx.x];
    #pragma unroll
    for (int j = 0; j < 4; ++j) {
        if (base + j < n) { offsets[base + j] = run; cursor[base + j] = run; run += c[j]; }
    }
    if (base == 0 && blockIdx.x == 0) offsets[n] = total;
}

// ---------------------------------------------------------------------------
__global__ void scatter_kernel(const int* __restrict__ T, int* __restrict__ cursor,
                               int2* __restrict__ rd, int E) {
    const int e = blockIdx.x * blockDim.x + threadIdx.x;
    if (e >= E) return;
    const int s = T[e];
    const int pos = atomicAdd(&cursor[s], 1);
    rd[pos] = make_int2(T[E + e], T[2 * E + e]);
}

// ---------------------------------------------------------------------------
// one wave per node: recompute w from q's, gather bf16 rows, normalize, elu.
// ---------------------------------------------------------------------------
__global__ void gather_kernel(const int* __restrict__ offsets, const int2* __restrict__ rd,
                              const float* __restrict__ q1, const float* __restrict__ q2,
                              const float* __restrict__ q3, const float* __restrict__ b_a2,
                              const unsigned* __restrict__ P2h, const unsigned* __restrict__ P3h,
                              float* __restrict__ out, int n) {
    const int node = (blockIdx.x << 2) + (threadIdx.x >> 6);   // 4 waves/block
    if (node >= n) return;
    const int lane = threadIdx.x & 63;
    const int lo = offsets[node], hi = offsets[node + 1];
    const float qn = q1[node] + b_a2[0];
    float ax = 0.f, ay = 0.f, wsum = 0.f;
    for (int i = lo; i < hi; ++i) {
        const int2 e = rd[i];
        float b = qn + q2[e.x] + q3[e.y];
        b = (b > 0.0f) ? b : 0.01f * b;
        const float wv = __expf(b);
        const unsigned v2 = P2h[(size_t)e.x * 64 + lane];
        const unsigned v3 = P3h[(size_t)e.y * 64 + lane];
        ax += wv * (unpack_lo(v2) + unpack_lo(v3));
        ay += wv * (unpack_hi(v2) + unpack_hi(v3));
        wsum += wv;
    }
    const float inv = 1.0f / wsum;
    const size_t o = (size_t)node * DIM + (lane << 1);
    const float v0 = out[o]     + ax * inv;
    const float v1 = out[o + 1] + ay * inv;
    out[o]     = (v0 > 0.0f) ? v0 : (__expf(v0) - 1.0f);
    out[o + 1] = (v1 > 0.0f) ? v1 : (__expf(v1) - 1.0f);
}

extern "C" void kernel_launch(void* const* d_in, const int* in_sizes, int n_in,
                              void* d_out, int out_size, void* d_ws, size_t ws_size,
                              hipStream_t stream) {
    const int*   T    = (const int*)d_in[0];
    const float* ent  = (const float*)d_in[1];
    const float* rel  = (const float*)d_in[2];
    const float* W_a  = (const float*)d_in[4];
    const float* b_a  = (const float*)d_in[5];
    const float* W_a2 = (const float*)d_in[6];
    const float* b_a2 = (const float*)d_in[7];
    float* out = (float*)d_out;

    const int E  = in_sizes[0] / 3;
    const int NE = in_sizes[1] / DIM;
    const int NR = in_sizes[2] / DIM;
    const int NB = (NE + 1023) / 1024;         // scan blocks (<=64 supported)
    const int NT = (NE + 15) / 16;             // 16-row MFMA tiles

    float* ws = (float*)d_ws;
    size_t off = 0;
    unsigned* P3h = (unsigned*)(ws + off); off += (size_t)NE * 64;
    unsigned* P2h = (unsigned*)(ws + off); off += (size_t)NR * 64;
    unsigned short* Wt = (unsigned short*)(ws + off); off += 256 * DIM / 2;  // 16B-aligned
    float* q1   = ws + off; off += NE;
    float* q3   = ws + off; off += NE;
    float* q2   = ws + off; off += NR + 64;
    int* counts  = (int*)(ws + off); off += NE;
    int* offsets = (int*)(ws + off); off += NE + 64;
    int* cursor  = (int*)(ws + off); off += NE;
    int* bsum    = (int*)(ws + off); off += 64;
    int* boff    = (int*)(ws + off); off += 64;
    int2* rd     = (int2*)(ws + off); off += (size_t)E * 2;

    // zero the histogram (graph replays: must re-init every call)
    hipMemsetAsync(counts, 0, (size_t)NE * sizeof(int), stream);

    // W transpose+bf16 pack for the MFMA B operand
    wprep_kernel<<<256, 128, 0, stream>>>(W_a, Wt);

    // MFMA dual projection (ent): P1b -> out, P3 -> bf16, q1/q3 fused
    proj_mfma_kernel<<<(NT + 3) / 4, 256, 0, stream>>>(ent, Wt, b_a, W_a2,
                                                       out, P3h, q1, q3, NE, NT);

    // rel projection (500 rows, VALU)
    proj_rel_kernel<<<(NR + 7) / 8, 128, 0, stream>>>(rel, W_a + 128 * DIM, W_a2, P2h, q2, NR);

    // per-source histogram
    hist_kernel<<<(E + 255) / 256, 256, 0, stream>>>(T, counts, E);

    // hierarchical CSR scan
    scan_bsum_kernel<<<NB, 256, 0, stream>>>(counts, bsum, NE);
    scan_boff_kernel<<<1, 64, 0, stream>>>(bsum, boff, NB);
    scan_write_kernel<<<NB, 256, 0, stream>>>(counts, boff, offsets, cursor, NE, E);

    // scatter edges into source-grouped order
    scatter_kernel<<<(E + 255) / 256, 256, 0, stream>>>(T, cursor, rd, E);

    // gather + softmax-normalize + elu (weights recomputed from q's)
    gather_kernel<<<(NE + 3) / 4, 256, 0, stream>>>(offsets, rd, q1, q2, q3, b_a2,
                                                    P2h, P3h, out, NE);
}

// Round 6
// 159.584 us; speedup vs baseline: 3.6199x; 1.1638x over previous
//
#include <hip/hip_runtime.h>

#define DIM 128

typedef __attribute__((ext_vector_type(8))) short bf16x8;
typedef __attribute__((ext_vector_type(4))) float f32x4;

// ---- bf16 helpers (RNE) ----------------------------------------------------
__device__ inline unsigned short to_bf16(float f) {
    unsigned u = __float_as_uint(f);
    u = (u + 0x7FFFu + ((u >> 16) & 1u)) >> 16;
    return (unsigned short)u;
}
__device__ inline unsigned pack_bf16(float lo, float hi) {
    return (unsigned)to_bf16(lo) | ((unsigned)to_bf16(hi) << 16);
}
__device__ inline float unpack_lo(unsigned v) { return __uint_as_float(v << 16); }
__device__ inline float unpack_hi(unsigned v) { return __uint_as_float(v & 0xFFFF0000u); }

// ---------------------------------------------------------------------------
// W prep: Wt[c][k] (bf16, c in 0..255) = W_a[k][c] for c<128 (W1 block),
//                                       = W_a[256+k][c-128] for c>=128 (W3 block)
// ---------------------------------------------------------------------------
__global__ void wprep_kernel(const float* __restrict__ W_a, unsigned short* __restrict__ Wt) {
    const int c = blockIdx.x;          // 0..255
    const int k = threadIdx.x;         // 0..127
    const int srow = (c < 128) ? k : (256 + k);
    const int scol = (c < 128) ? c : (c - 128);
    Wt[c * DIM + k] = to_bf16(W_a[srow * DIM + scol]);
}

// ---------------------------------------------------------------------------
// MFMA dual projection over ent rows (16 rows per wave, 4 waves/block):
//   P1 = ent@W1 + b_a -> out (fp32), P3 = ent@W3 -> P3h (packed bf16)
//   q1 = P1b·Wa2, q3 = P3·Wa2
// ---------------------------------------------------------------------------
__global__ __launch_bounds__(256) void proj_mfma_kernel(
        const float* __restrict__ ent, const unsigned short* __restrict__ Wt,
        const float* __restrict__ b_a, const float* __restrict__ Wa2,
        float* __restrict__ out, unsigned* __restrict__ P3h,
        float* __restrict__ q1, float* __restrict__ q3, int n, int ntiles) {
    const int tile = blockIdx.x * 4 + (threadIdx.x >> 6);
    if (tile >= ntiles) return;
    const int lane = threadIdx.x & 63;
    const int g = lane >> 4;           // k-group / row-group
    const int m = lane & 15;           // A row within tile; C col within tile
    const int row0 = tile * 16;

    const int rowA = min(row0 + m, n - 1);
    const float* arow = ent + (size_t)rowA * DIM;
    bf16x8 afrag[4];
    #pragma unroll
    for (int kk = 0; kk < 4; ++kk) {
        const float4 u0 = *(const float4*)(arow + kk * 32 + g * 8);
        const float4 u1 = *(const float4*)(arow + kk * 32 + g * 8 + 4);
        bf16x8 a;
        a[0] = (short)to_bf16(u0.x); a[1] = (short)to_bf16(u0.y);
        a[2] = (short)to_bf16(u0.z); a[3] = (short)to_bf16(u0.w);
        a[4] = (short)to_bf16(u1.x); a[5] = (short)to_bf16(u1.y);
        a[6] = (short)to_bf16(u1.z); a[7] = (short)to_bf16(u1.w);
        afrag[kk] = a;
    }

    float qp1[4] = {0.f, 0.f, 0.f, 0.f};
    float qp3[4] = {0.f, 0.f, 0.f, 0.f};

    #pragma unroll
    for (int ct = 0; ct < 16; ++ct) {
        f32x4 acc = {0.f, 0.f, 0.f, 0.f};
        #pragma unroll
        for (int kk = 0; kk < 4; ++kk) {
            const bf16x8 b = *(const bf16x8*)(Wt + (ct * 16 + m) * DIM + kk * 32 + g * 8);
            acc = __builtin_amdgcn_mfma_f32_16x16x32_bf16(afrag[kk], b, acc, 0, 0, 0);
        }
        const int c = ct * 16 + m;     // 0..255 combined column
        if (ct < 8) {
            const float bias = b_a[c];
            const float wa2  = Wa2[c];
            #pragma unroll
            for (int r = 0; r < 4; ++r) {
                const int row = row0 + g * 4 + r;
                const float v = acc[r] + bias;
                if (row < n) out[(size_t)row * DIM + c] = v;
                qp1[r] += v * wa2;
            }
        } else {
            const int c3 = c - 128;    // 0..127
            const float wa2 = Wa2[c3];
            #pragma unroll
            for (int r = 0; r < 4; ++r) {
                const int row = row0 + g * 4 + r;
                const float v = acc[r];
                qp3[r] += v * wa2;
                const float partner = __shfl_xor(v, 1);
                if ((m & 1) == 0 && row < n)
                    P3h[(size_t)row * 64 + (c3 >> 1)] = pack_bf16(v, partner);
            }
        }
    }

    #pragma unroll
    for (int r = 0; r < 4; ++r) {
        float v1 = qp1[r], v3 = qp3[r];
        #pragma unroll
        for (int o = 1; o < 16; o <<= 1) {
            v1 += __shfl_xor(v1, o);
            v3 += __shfl_xor(v3, o);
        }
        const int row = row0 + g * 4 + r;
        if (m == 0 && row < n) { q1[row] = v1; q3[row] = v3; }
    }
}

// ---------------------------------------------------------------------------
// Single projection (rel, 500 rows): P2 = rel@W2 -> bf16 packed, q2 = P2·Wa2
// ---------------------------------------------------------------------------
__global__ void proj_rel_kernel(const float* __restrict__ X, const float* __restrict__ W,
                                const float* __restrict__ Wa2, unsigned* __restrict__ Ph,
                                float* __restrict__ q, int n) {
    __shared__ float xs[8][DIM];
    __shared__ float sred[8][2];
    const int t = threadIdx.x;
    const int row0 = blockIdx.x * 8;
    #pragma unroll
    for (int e = 0; e < 8; ++e) {
        int row = row0 + e;
        xs[e][t] = (row < n) ? X[(size_t)row * DIM + t] : 0.0f;
    }
    __syncthreads();
    float acc[8] = {0,0,0,0,0,0,0,0};
    #pragma unroll 4
    for (int k = 0; k < DIM; ++k) {
        const float wv = W[k * DIM + t];
        #pragma unroll
        for (int e = 0; e < 8; ++e) acc[e] += xs[e][k] * wv;
    }
    const float wa2 = Wa2[t];
    const int wid = t >> 6, lane = t & 63;
    #pragma unroll
    for (int e = 0; e < 8; ++e) {
        float v = acc[e] * wa2;
        #pragma unroll
        for (int o = 32; o > 0; o >>= 1) v += __shfl_down(v, o);
        if (lane == 0) sred[e][wid] = v;
    }
    __syncthreads();
    #pragma unroll
    for (int e = 0; e < 8; ++e) {
        int row = row0 + e;
        float hi = __shfl_down(acc[e], 1);
        if (row < n && (t & 1) == 0) Ph[(size_t)row * 64 + (t >> 1)] = pack_bf16(acc[e], hi);
    }
    if (t < 8) {
        int row = row0 + t;
        if (row < n) q[row] = sred[t][0] + sred[t][1];
    }
}

// ---------------------------------------------------------------------------
__global__ void hist_kernel(const int* __restrict__ T, int* __restrict__ counts, int E) {
    const int e = blockIdx.x * blockDim.x + threadIdx.x;
    if (e < E) atomicAdd(&counts[T[e]], 1);
}

// ---------------------------------------------------------------------------
__device__ inline int wave_incl_scan(int v) {
    const int lane = threadIdx.x & 63;
    #pragma unroll
    for (int o = 1; o < 64; o <<= 1) {
        int u = __shfl_up(v, o);
        if (lane >= o) v += u;
    }
    return v;
}

__global__ void scan_bsum_kernel(const int* __restrict__ counts, int* __restrict__ bsum, int n) {
    const int t = threadIdx.x;                 // 256
    const int base = blockIdx.x * 1024 + t * 4;
    int s = 0;
    #pragma unroll
    for (int j = 0; j < 4; ++j) if (base + j < n) s += counts[base + j];
    #pragma unroll
    for (int o = 32; o > 0; o >>= 1) s += __shfl_down(s, o);
    __shared__ int ws[4];
    if ((t & 63) == 0) ws[t >> 6] = s;
    __syncthreads();
    if (t == 0) bsum[blockIdx.x] = ws[0] + ws[1] + ws[2] + ws[3];
}

__global__ void scan_boff_kernel(const int* __restrict__ bsum, int* __restrict__ boff, int nb) {
    const int lane = threadIdx.x;              // 64
    int v = (lane < nb) ? bsum[lane] : 0;
    int incl = wave_incl_scan(v);
    if (lane < nb) boff[lane] = incl - v;
}

__global__ void scan_write_kernel(const int* __restrict__ counts, const int* __restrict__ boff,
                                  int* __restrict__ offsets, int* __restrict__ cursor,
                                  int n, int total) {
    const int t = threadIdx.x;                 // 256
    const int base = blockIdx.x * 1024 + t * 4;
    int c[4];
    int s = 0;
    #pragma unroll
    for (int j = 0; j < 4; ++j) {
        c[j] = (base + j < n) ? counts[base + j] : 0;
        s += c[j];
    }
    int incl = wave_incl_scan(s);
    __shared__ int wsum[4], wpre[4];
    const int wid = t >> 6, lane = t & 63;
    if (lane == 63) wsum[wid] = incl;
    __syncthreads();
    if (t == 0) {
        int run = 0;
        #pragma unroll
        for (int k = 0; k < 4; ++k) { wpre[k] = run; run += wsum[k]; }
    }
    __syncthreads();
    int run = incl - s + wpre[wid] + boff[blockIdx.x];
    #pragma unroll
    for (int j = 0; j < 4; ++j) {
        if (base + j < n) { offsets[base + j] = run; cursor[base + j] = run; run += c[j]; }
    }
    if (base == 0 && blockIdx.x == 0) offsets[n] = total;
}

// ---------------------------------------------------------------------------
// fused weight + scatter: w = exp(lrelu(q1[s]+q2[r]+q3[d]+b_a2));
// payload packed to 8 B: {(r<<17)|d, w}   (requires NR<2^15, NE<2^17)
// ---------------------------------------------------------------------------
__global__ void scatter_kernel(const int* __restrict__ T, const float* __restrict__ q1,
                               const float* __restrict__ q2, const float* __restrict__ q3,
                               const float* __restrict__ b_a2, int* __restrict__ cursor,
                               uint2* __restrict__ rdw, int E) {
    const int e = blockIdx.x * blockDim.x + threadIdx.x;
    if (e >= E) return;
    const int s = T[e], r = T[E + e], d = T[2 * E + e];
    float b = q1[s] + q2[r] + q3[d] + b_a2[0];
    b = (b > 0.0f) ? b : 0.01f * b;
    const float wv = __expf(b);
    const int pos = atomicAdd(&cursor[s], 1);
    rdw[pos] = make_uint2(((unsigned)r << 17) | (unsigned)d, __float_as_uint(wv));
}

// ---------------------------------------------------------------------------
// one wave per node, unrolled x2: gather bf16 rows, normalize, elu.
// P1b (= P1 + b_a) lives in `out`; read-then-overwrite per element.
// ---------------------------------------------------------------------------
__global__ void gather_kernel(const int* __restrict__ offsets, const uint2* __restrict__ rdw,
                              const unsigned* __restrict__ P2h, const unsigned* __restrict__ P3h,
                              float* __restrict__ out, int n) {
    const int node = (blockIdx.x << 2) + (threadIdx.x >> 6);   // 4 waves/block
    if (node >= n) return;
    const int lane = threadIdx.x & 63;
    const int lo = offsets[node], hi = offsets[node + 1];
    float ax0 = 0.f, ay0 = 0.f, ws0 = 0.f;
    float ax1 = 0.f, ay1 = 0.f, ws1 = 0.f;
    int i = lo;
    for (; i + 1 < hi; i += 2) {
        const uint2 e0 = rdw[i];
        const uint2 e1 = rdw[i + 1];
        const unsigned v2a = P2h[(size_t)(e0.x >> 17) * 64 + lane];
        const unsigned v3a = P3h[(size_t)(e0.x & 0x1FFFFu) * 64 + lane];
        const unsigned v2b = P2h[(size_t)(e1.x >> 17) * 64 + lane];
        const unsigned v3b = P3h[(size_t)(e1.x & 0x1FFFFu) * 64 + lane];
        const float wa = __uint_as_float(e0.y);
        const float wb = __uint_as_float(e1.y);
        ax0 += wa * (unpack_lo(v2a) + unpack_lo(v3a));
        ay0 += wa * (unpack_hi(v2a) + unpack_hi(v3a));
        ws0 += wa;
        ax1 += wb * (unpack_lo(v2b) + unpack_lo(v3b));
        ay1 += wb * (unpack_hi(v2b) + unpack_hi(v3b));
        ws1 += wb;
    }
    if (i < hi) {
        const uint2 e0 = rdw[i];
        const unsigned v2a = P2h[(size_t)(e0.x >> 17) * 64 + lane];
        const unsigned v3a = P3h[(size_t)(e0.x & 0x1FFFFu) * 64 + lane];
        const float wa = __uint_as_float(e0.y);
        ax0 += wa * (unpack_lo(v2a) + unpack_lo(v3a));
        ay0 += wa * (unpack_hi(v2a) + unpack_hi(v3a));
        ws0 += wa;
    }
    const float inv = 1.0f / (ws0 + ws1);
    const float ax = ax0 + ax1, ay = ay0 + ay1;
    const size_t o = (size_t)node * DIM + (lane << 1);
    const float v0 = out[o]     + ax * inv;
    const float v1 = out[o + 1] + ay * inv;
    out[o]     = (v0 > 0.0f) ? v0 : (__expf(v0) - 1.0f);
    out[o + 1] = (v1 > 0.0f) ? v1 : (__expf(v1) - 1.0f);
}

extern "C" void kernel_launch(void* const* d_in, const int* in_sizes, int n_in,
                              void* d_out, int out_size, void* d_ws, size_t ws_size,
                              hipStream_t stream) {
    const int*   T    = (const int*)d_in[0];
    const float* ent  = (const float*)d_in[1];
    const float* rel  = (const float*)d_in[2];
    const float* W_a  = (const float*)d_in[4];
    const float* b_a  = (const float*)d_in[5];
    const float* W_a2 = (const float*)d_in[6];
    const float* b_a2 = (const float*)d_in[7];
    float* out = (float*)d_out;

    const int E  = in_sizes[0] / 3;
    const int NE = in_sizes[1] / DIM;
    const int NR = in_sizes[2] / DIM;
    const int NB = (NE + 1023) / 1024;         // scan blocks (<=64 supported)
    const int NT = (NE + 15) / 16;             // 16-row MFMA tiles

    float* ws = (float*)d_ws;
    size_t off = 0;
    unsigned* P3h = (unsigned*)(ws + off); off += (size_t)NE * 64;
    unsigned* P2h = (unsigned*)(ws + off); off += (size_t)NR * 64;
    unsigned short* Wt = (unsigned short*)(ws + off); off += 256 * DIM / 2;
    float* q1   = ws + off; off += NE;
    float* q3   = ws + off; off += NE;
    float* q2   = ws + off; off += NR + 64;
    int* counts  = (int*)(ws + off); off += NE;
    int* offsets = (int*)(ws + off); off += NE + 64;
    int* cursor  = (int*)(ws + off); off += NE;
    int* bsum    = (int*)(ws + off); off += 64;
    int* boff    = (int*)(ws + off); off += 64;
    uint2* rdw   = (uint2*)(ws + off); off += (size_t)E * 2;

    // zero the histogram (graph replays: must re-init every call)
    hipMemsetAsync(counts, 0, (size_t)NE * sizeof(int), stream);

    // W transpose+bf16 pack for the MFMA B operand
    wprep_kernel<<<256, 128, 0, stream>>>(W_a, Wt);

    // MFMA dual projection (ent): P1b -> out, P3 -> bf16, q1/q3 fused
    proj_mfma_kernel<<<(NT + 3) / 4, 256, 0, stream>>>(ent, Wt, b_a, W_a2,
                                                       out, P3h, q1, q3, NE, NT);

    // rel projection (500 rows, VALU)
    proj_rel_kernel<<<(NR + 7) / 8, 128, 0, stream>>>(rel, W_a + 128 * DIM, W_a2, P2h, q2, NR);

    // per-source histogram
    hist_kernel<<<(E + 255) / 256, 256, 0, stream>>>(T, counts, E);

    // hierarchical CSR scan
    scan_bsum_kernel<<<NB, 256, 0, stream>>>(counts, bsum, NE);
    scan_boff_kernel<<<1, 64, 0, stream>>>(bsum, boff, NB);
    scan_write_kernel<<<NB, 256, 0, stream>>>(counts, boff, offsets, cursor, NE, E);

    // fused weight + scatter (8 B payload per edge)
    scatter_kernel<<<(E + 255) / 256, 256, 0, stream>>>(T, q1, q2, q3, b_a2, cursor, rdw, E);

    // gather + normalize + elu (no scalar gathers, unrolled x2)
    gather_kernel<<<(NE + 3) / 4, 256, 0, stream>>>(offsets, rdw, P2h, P3h, out, NE);
}

// Round 7
// 151.238 us; speedup vs baseline: 3.8196x; 1.0552x over previous
//
#include <hip/hip_runtime.h>

#define DIM 128

typedef __attribute__((ext_vector_type(8))) short bf16x8;
typedef __attribute__((ext_vector_type(4))) float f32x4;

// ---- bf16 helpers (RNE) ----------------------------------------------------
__device__ inline unsigned short to_bf16(float f) {
    unsigned u = __float_as_uint(f);
    u = (u + 0x7FFFu + ((u >> 16) & 1u)) >> 16;
    return (unsigned short)u;
}
__device__ inline unsigned pack_bf16(float lo, float hi) {
    return (unsigned)to_bf16(lo) | ((unsigned)to_bf16(hi) << 16);
}
__device__ inline float unpack_lo(unsigned v) { return __uint_as_float(v << 16); }
__device__ inline float unpack_hi(unsigned v) { return __uint_as_float(v & 0xFFFF0000u); }

// ---------------------------------------------------------------------------
// W prep: Wt[c][k] (bf16, c in 0..255) = W_a[k][c] for c<128 (W1 block),
//                                       = W_a[256+k][c-128] for c>=128 (W3 block)
// ---------------------------------------------------------------------------
__global__ void wprep_kernel(const float* __restrict__ W_a, unsigned short* __restrict__ Wt) {
    const int c = blockIdx.x;          // 0..255
    const int k = threadIdx.x;         // 0..127
    const int srow = (c < 128) ? k : (256 + k);
    const int scol = (c < 128) ? c : (c - 128);
    Wt[c * DIM + k] = to_bf16(W_a[srow * DIM + scol]);
}

// ---------------------------------------------------------------------------
// MFMA projection over ent rows, 2 waves per 16-row tile:
//   half=0: P1b = ent@W1 + b_a -> P1h (bf16), q1 = P1b·Wa2
//   half=1: P3  = ent@W3       -> P3h (bf16), q3 = P3·Wa2
// A frag: lane holds ent[row0+(l&15)][kk*32 + (l>>4)*8 + i]  (8 contig k)
// B frag: lane holds Wt[half*128 + ct*16+(l&15)][same k map]
// C/D   : reg r -> row=(l>>4)*4+r, col=l&15   [HW-verified]
// ---------------------------------------------------------------------------
__global__ __launch_bounds__(256) void proj_mfma_kernel(
        const float* __restrict__ ent, const unsigned short* __restrict__ Wt,
        const float* __restrict__ b_a, const float* __restrict__ Wa2,
        unsigned* __restrict__ P1h, unsigned* __restrict__ P3h,
        float* __restrict__ q1, float* __restrict__ q3, int n, int ntiles2) {
    const int tile2 = blockIdx.x * 4 + (threadIdx.x >> 6);
    if (tile2 >= ntiles2) return;
    const int half = tile2 & 1;
    const int rowtile = tile2 >> 1;
    const int lane = threadIdx.x & 63;
    const int g = lane >> 4;           // k-group / row-group
    const int m = lane & 15;           // A row within tile; C col within tile
    const int row0 = rowtile * 16;

    // ---- load + convert A fragments (16 rows of ent)
    const int rowA = min(row0 + m, n - 1);
    const float* arow = ent + (size_t)rowA * DIM;
    bf16x8 afrag[4];
    #pragma unroll
    for (int kk = 0; kk < 4; ++kk) {
        const float4 u0 = *(const float4*)(arow + kk * 32 + g * 8);
        const float4 u1 = *(const float4*)(arow + kk * 32 + g * 8 + 4);
        bf16x8 a;
        a[0] = (short)to_bf16(u0.x); a[1] = (short)to_bf16(u0.y);
        a[2] = (short)to_bf16(u0.z); a[3] = (short)to_bf16(u0.w);
        a[4] = (short)to_bf16(u1.x); a[5] = (short)to_bf16(u1.y);
        a[6] = (short)to_bf16(u1.z); a[7] = (short)to_bf16(u1.w);
        afrag[kk] = a;
    }

    unsigned* __restrict__ Ph = half ? P3h : P1h;
    float*    __restrict__ qo = half ? q3  : q1;
    const unsigned short* Wh = Wt + half * 128 * DIM;

    float qp[4] = {0.f, 0.f, 0.f, 0.f};

    #pragma unroll
    for (int ct = 0; ct < 8; ++ct) {
        f32x4 acc = {0.f, 0.f, 0.f, 0.f};
        #pragma unroll
        for (int kk = 0; kk < 4; ++kk) {
            const bf16x8 b = *(const bf16x8*)(Wh + (ct * 16 + m) * DIM + kk * 32 + g * 8);
            acc = __builtin_amdgcn_mfma_f32_16x16x32_bf16(afrag[kk], b, acc, 0, 0, 0);
        }
        const int c = ct * 16 + m;     // 0..127 output column
        const float bias = half ? 0.0f : b_a[c];
        const float wa2  = Wa2[c];
        #pragma unroll
        for (int r = 0; r < 4; ++r) {
            const int row = row0 + g * 4 + r;
            const float v = acc[r] + bias;
            qp[r] += v * wa2;
            const float partner = __shfl_xor(v, 1);
            if ((m & 1) == 0 && row < n)
                Ph[(size_t)row * 64 + (c >> 1)] = pack_bf16(v, partner);
        }
    }

    // ---- reduce q over the 16 lanes of each row-group and store
    #pragma unroll
    for (int r = 0; r < 4; ++r) {
        float v = qp[r];
        #pragma unroll
        for (int o = 1; o < 16; o <<= 1) v += __shfl_xor(v, o);
        const int row = row0 + g * 4 + r;
        if (m == 0 && row < n) qo[row] = v;
    }
}

// ---------------------------------------------------------------------------
// Single projection (rel, 500 rows): P2 = rel@W2 -> bf16 packed, q2 = P2·Wa2
// ---------------------------------------------------------------------------
__global__ void proj_rel_kernel(const float* __restrict__ X, const float* __restrict__ W,
                                const float* __restrict__ Wa2, unsigned* __restrict__ Ph,
                                float* __restrict__ q, int n) {
    __shared__ float xs[8][DIM];
    __shared__ float sred[8][2];
    const int t = threadIdx.x;
    const int row0 = blockIdx.x * 8;
    #pragma unroll
    for (int e = 0; e < 8; ++e) {
        int row = row0 + e;
        xs[e][t] = (row < n) ? X[(size_t)row * DIM + t] : 0.0f;
    }
    __syncthreads();
    float acc[8] = {0,0,0,0,0,0,0,0};
    #pragma unroll 4
    for (int k = 0; k < DIM; ++k) {
        const float wv = W[k * DIM + t];
        #pragma unroll
        for (int e = 0; e < 8; ++e) acc[e] += xs[e][k] * wv;
    }
    const float wa2 = Wa2[t];
    const int wid = t >> 6, lane = t & 63;
    #pragma unroll
    for (int e = 0; e < 8; ++e) {
        float v = acc[e] * wa2;
        #pragma unroll
        for (int o = 32; o > 0; o >>= 1) v += __shfl_down(v, o);
        if (lane == 0) sred[e][wid] = v;
    }
    __syncthreads();
    #pragma unroll
    for (int e = 0; e < 8; ++e) {
        int row = row0 + e;
        float hi = __shfl_down(acc[e], 1);
        if (row < n && (t & 1) == 0) Ph[(size_t)row * 64 + (t >> 1)] = pack_bf16(acc[e], hi);
    }
    if (t < 8) {
        int row = row0 + t;
        if (row < n) q[row] = sred[t][0] + sred[t][1];
    }
}

// ---------------------------------------------------------------------------
__global__ void hist_kernel(const int* __restrict__ T, int* __restrict__ counts, int E) {
    const int e = blockIdx.x * blockDim.x + threadIdx.x;
    if (e < E) atomicAdd(&counts[T[e]], 1);
}

// ---------------------------------------------------------------------------
__device__ inline int wave_incl_scan(int v) {
    const int lane = threadIdx.x & 63;
    #pragma unroll
    for (int o = 1; o < 64; o <<= 1) {
        int u = __shfl_up(v, o);
        if (lane >= o) v += u;
    }
    return v;
}

__global__ void scan_bsum_kernel(const int* __restrict__ counts, int* __restrict__ bsum, int n) {
    const int t = threadIdx.x;                 // 256
    const int base = blockIdx.x * 1024 + t * 4;
    int s = 0;
    #pragma unroll
    for (int j = 0; j < 4; ++j) if (base + j < n) s += counts[base + j];
    #pragma unroll
    for (int o = 32; o > 0; o >>= 1) s += __shfl_down(s, o);
    __shared__ int ws[4];
    if ((t & 63) == 0) ws[t >> 6] = s;
    __syncthreads();
    if (t == 0) bsum[blockIdx.x] = ws[0] + ws[1] + ws[2] + ws[3];
}

__global__ void scan_boff_kernel(const int* __restrict__ bsum, int* __restrict__ boff, int nb) {
    const int lane = threadIdx.x;              // 64
    int v = (lane < nb) ? bsum[lane] : 0;
    int incl = wave_incl_scan(v);
    if (lane < nb) boff[lane] = incl - v;
}

__global__ void scan_write_kernel(const int* __restrict__ counts, const int* __restrict__ boff,
                                  int* __restrict__ offsets, int* __restrict__ cursor,
                                  int n, int total) {
    const int t = threadIdx.x;                 // 256
    const int base = blockIdx.x * 1024 + t * 4;
    int c[4];
    int s = 0;
    #pragma unroll
    for (int j = 0; j < 4; ++j) {
        c[j] = (base + j < n) ? counts[base + j] : 0;
        s += c[j];
    }
    int incl = wave_incl_scan(s);
    __shared__ int wsum[4], wpre[4];
    const int wid = t >> 6, lane = t & 63;
    if (lane == 63) wsum[wid] = incl;
    __syncthreads();
    if (t == 0) {
        int run = 0;
        #pragma unroll
        for (int k = 0; k < 4; ++k) { wpre[k] = run; run += wsum[k]; }
    }
    __syncthreads();
    int run = incl - s + wpre[wid] + boff[blockIdx.x];
    #pragma unroll
    for (int j = 0; j < 4; ++j) {
        if (base + j < n) { offsets[base + j] = run; cursor[base + j] = run; run += c[j]; }
    }
    if (base == 0 && blockIdx.x == 0) offsets[n] = total;
}

// ---------------------------------------------------------------------------
// fused weight + scatter: w = exp(lrelu(q1[s]+q2[r]+q3[d]+b_a2));
// payload packed to 8 B: {(r<<17)|d, w}   (requires NR<2^15, NE<2^17)
// ---------------------------------------------------------------------------
__global__ void scatter_kernel(const int* __restrict__ T, const float* __restrict__ q1,
                               const float* __restrict__ q2, const float* __restrict__ q3,
                               const float* __restrict__ b_a2, int* __restrict__ cursor,
                               uint2* __restrict__ rdw, int E) {
    const int e = blockIdx.x * blockDim.x + threadIdx.x;
    if (e >= E) return;
    const int s = T[e], r = T[E + e], d = T[2 * E + e];
    float b = q1[s] + q2[r] + q3[d] + b_a2[0];
    b = (b > 0.0f) ? b : 0.01f * b;
    const float wv = __expf(b);
    const int pos = atomicAdd(&cursor[s], 1);
    rdw[pos] = make_uint2(((unsigned)r << 17) | (unsigned)d, __float_as_uint(wv));
}

// ---------------------------------------------------------------------------
// one wave per node, unrolled x4: gather bf16 rows, normalize, add P1b, elu.
// out is WRITE-ONLY (float2 per lane).
// ---------------------------------------------------------------------------
__global__ void gather_kernel(const int* __restrict__ offsets, const uint2* __restrict__ rdw,
                              const unsigned* __restrict__ P1h, const unsigned* __restrict__ P2h,
                              const unsigned* __restrict__ P3h, float* __restrict__ out, int n) {
    const int node = (blockIdx.x << 2) + (threadIdx.x >> 6);   // 4 waves/block
    if (node >= n) return;
    const int lane = threadIdx.x & 63;
    const int lo = offsets[node], hi = offsets[node + 1];
    float axp[4] = {0.f,0.f,0.f,0.f};
    float ayp[4] = {0.f,0.f,0.f,0.f};
    float wsp[4] = {0.f,0.f,0.f,0.f};
    int i = lo;
    for (; i + 3 < hi; i += 4) {
        uint2 e[4];
        #pragma unroll
        for (int j = 0; j < 4; ++j) e[j] = rdw[i + j];
        unsigned v2[4], v3[4];
        #pragma unroll
        for (int j = 0; j < 4; ++j) {
            v2[j] = P2h[(size_t)(e[j].x >> 17) * 64 + lane];
            v3[j] = P3h[(size_t)(e[j].x & 0x1FFFFu) * 64 + lane];
        }
        #pragma unroll
        for (int j = 0; j < 4; ++j) {
            const float wv = __uint_as_float(e[j].y);
            axp[j] += wv * (unpack_lo(v2[j]) + unpack_lo(v3[j]));
            ayp[j] += wv * (unpack_hi(v2[j]) + unpack_hi(v3[j]));
            wsp[j] += wv;
        }
    }
    for (; i < hi; ++i) {
        const uint2 e0 = rdw[i];
        const unsigned v2a = P2h[(size_t)(e0.x >> 17) * 64 + lane];
        const unsigned v3a = P3h[(size_t)(e0.x & 0x1FFFFu) * 64 + lane];
        const float wv = __uint_as_float(e0.y);
        axp[0] += wv * (unpack_lo(v2a) + unpack_lo(v3a));
        ayp[0] += wv * (unpack_hi(v2a) + unpack_hi(v3a));
        wsp[0] += wv;
    }
    const float ax = (axp[0] + axp[1]) + (axp[2] + axp[3]);
    const float ay = (ayp[0] + ayp[1]) + (ayp[2] + ayp[3]);
    const float inv = 1.0f / ((wsp[0] + wsp[1]) + (wsp[2] + wsp[3]));
    const unsigned p1 = P1h[(size_t)node * 64 + lane];
    float v0 = unpack_lo(p1) + ax * inv;
    float v1 = unpack_hi(p1) + ay * inv;
    v0 = (v0 > 0.0f) ? v0 : (__expf(v0) - 1.0f);
    v1 = (v1 > 0.0f) ? v1 : (__expf(v1) - 1.0f);
    *(float2*)(out + (size_t)node * DIM + (lane << 1)) = make_float2(v0, v1);
}

extern "C" void kernel_launch(void* const* d_in, const int* in_sizes, int n_in,
                              void* d_out, int out_size, void* d_ws, size_t ws_size,
                              hipStream_t stream) {
    const int*   T    = (const int*)d_in[0];
    const float* ent  = (const float*)d_in[1];
    const float* rel  = (const float*)d_in[2];
    const float* W_a  = (const float*)d_in[4];
    const float* b_a  = (const float*)d_in[5];
    const float* W_a2 = (const float*)d_in[6];
    const float* b_a2 = (const float*)d_in[7];
    float* out = (float*)d_out;

    const int E  = in_sizes[0] / 3;
    const int NE = in_sizes[1] / DIM;
    const int NR = in_sizes[2] / DIM;
    const int NB = (NE + 1023) / 1024;         // scan blocks (<=64 supported)
    const int NT2 = ((NE + 15) / 16) * 2;      // 16-row MFMA tiles x 2 halves

    float* ws = (float*)d_ws;
    size_t off = 0;
    unsigned* P1h = (unsigned*)(ws + off); off += (size_t)NE * 64;
    unsigned* P3h = (unsigned*)(ws + off); off += (size_t)NE * 64;
    unsigned* P2h = (unsigned*)(ws + off); off += (size_t)NR * 64;
    unsigned short* Wt = (unsigned short*)(ws + off); off += 256 * DIM / 2;
    float* q1   = ws + off; off += NE;
    float* q3   = ws + off; off += NE;
    float* q2   = ws + off; off += NR + 64;
    int* counts  = (int*)(ws + off); off += NE;
    int* offsets = (int*)(ws + off); off += NE + 64;
    int* cursor  = (int*)(ws + off); off += NE;
    int* bsum    = (int*)(ws + off); off += 64;
    int* boff    = (int*)(ws + off); off += 64;
    uint2* rdw   = (uint2*)(ws + off); off += (size_t)E * 2;

    // zero the histogram (graph replays: must re-init every call)
    hipMemsetAsync(counts, 0, (size_t)NE * sizeof(int), stream);

    // W transpose+bf16 pack for the MFMA B operand
    wprep_kernel<<<256, 128, 0, stream>>>(W_a, Wt);

    // MFMA projection (ent): 2 waves per row-tile (W1->P1h+q1, W3->P3h+q3)
    proj_mfma_kernel<<<(NT2 + 3) / 4, 256, 0, stream>>>(ent, Wt, b_a, W_a2,
                                                        P1h, P3h, q1, q3, NE, NT2);

    // rel projection (500 rows, VALU)
    proj_rel_kernel<<<(NR + 7) / 8, 128, 0, stream>>>(rel, W_a + 128 * DIM, W_a2, P2h, q2, NR);

    // per-source histogram
    hist_kernel<<<(E + 255) / 256, 256, 0, stream>>>(T, counts, E);

    // hierarchical CSR scan
    scan_bsum_kernel<<<NB, 256, 0, stream>>>(counts, bsum, NE);
    scan_boff_kernel<<<1, 64, 0, stream>>>(bsum, boff, NB);
    scan_write_kernel<<<NB, 256, 0, stream>>>(counts, boff, offsets, cursor, NE, E);

    // fused weight + scatter (8 B payload per edge)
    scatter_kernel<<<(E + 255) / 256, 256, 0, stream>>>(T, q1, q2, q3, b_a2, cursor, rdw, E);

    // gather + normalize + elu (write-only out, unrolled x4)
    gather_kernel<<<(NE + 3) / 4, 256, 0, stream>>>(offsets, rdw, P1h, P2h, P3h, out, NE);
}

// Round 8
// 122.609 us; speedup vs baseline: 4.7115x; 1.2335x over previous
//
#include <hip/hip_runtime.h>

#define DIM 128

typedef __attribute__((ext_vector_type(8))) short bf16x8;
typedef __attribute__((ext_vector_type(4))) float f32x4;

// ---- bf16 helpers (RNE) ----------------------------------------------------
__device__ inline unsigned short to_bf16(float f) {
    unsigned u = __float_as_uint(f);
    u = (u + 0x7FFFu + ((u >> 16) & 1u)) >> 16;
    return (unsigned short)u;
}
__device__ inline unsigned pack_bf16(float lo, float hi) {
    return (unsigned)to_bf16(lo) | ((unsigned)to_bf16(hi) << 16);
}
__device__ inline float unpack_lo(unsigned v) { return __uint_as_float(v << 16); }
__device__ inline float unpack_hi(unsigned v) { return __uint_as_float(v & 0xFFFF0000u); }

// ---------------------------------------------------------------------------
// W prep: Wt[c][k] (bf16, c in 0..255) = W_a[k][c] (c<128) | W_a[256+k][c-128]
// Also zeroes the histogram (replaces a separate memset dispatch).
// ---------------------------------------------------------------------------
__global__ void wprep_kernel(const float* __restrict__ W_a, unsigned short* __restrict__ Wt,
                             int* __restrict__ counts, int n) {
    const int c = blockIdx.x;          // 0..255
    const int k = threadIdx.x;         // 0..127
    const int srow = (c < 128) ? k : (256 + k);
    const int scol = (c < 128) ? c : (c - 128);
    Wt[c * DIM + k] = to_bf16(W_a[srow * DIM + scol]);
    for (int i = blockIdx.x * 128 + k; i < n; i += 256 * 128) counts[i] = 0;
}

// ---------------------------------------------------------------------------
// Fused stage 1: block roles (in dispatch order so hist fills CUs first):
//   [0, HB)          : histogram counts[src]++  (grid-stride)
//   [HB, HB+RB)      : rel projection -> P2h (bf16) + q2
//   [HB+RB, ...)     : ent MFMA projection, 2 waves/16-row tile:
//                      half=0: P1b=ent@W1+b_a -> P1h, q1;  half=1: P3 -> P3h, q3
// Proj epilogue: per-lane ds_write_b16 (pad stride 130) then 16 coalesced
// 256B dword stores per wave — no shfl packing, no scattered global stores.
// ---------------------------------------------------------------------------
__global__ __launch_bounds__(256) void stage1_kernel(
        const float* __restrict__ ent, const float* __restrict__ rel,
        const int* __restrict__ T, const unsigned short* __restrict__ Wt,
        const float* __restrict__ W_rel, const float* __restrict__ b_a,
        const float* __restrict__ Wa2,
        unsigned* __restrict__ P1h, unsigned* __restrict__ P3h, unsigned* __restrict__ P2h,
        float* __restrict__ q1, float* __restrict__ q3, float* __restrict__ q2,
        int* __restrict__ counts, int NE, int NR, int E, int NT2, int HB, int RB) {
    __shared__ unsigned smem[4288];    // 17 KB, shared by all paths
    int b = blockIdx.x;
    const int t = threadIdx.x;

    // ---------------- histogram path ----------------
    if (b < HB) {
        for (int e = b * 256 + t; e < E; e += HB * 256)
            atomicAdd(&counts[T[e]], 1);
        return;
    }
    b -= HB;

    // ---------------- rel projection path ----------------
    if (b < RB) {
        float* xs   = (float*)smem;            // [8][DIM]
        float* sred = (float*)(smem + 1024);   // [8][2]
        const int row0 = b * 8;
        #pragma unroll
        for (int e = 0; e < 8; ++e) {
            int row = row0 + e;
            xs[e * DIM + t % DIM + (t / DIM) * 0] = 0.0f; // placeholder avoided below
        }
        // (128 threads per row-chunk: use t<128 semantics — block is 256 threads,
        //  split into two halves each covering 4 rows)
        const int half = t >> 7;               // 0..1
        const int tc   = t & 127;              // column
        #pragma unroll
        for (int e = 0; e < 4; ++e) {
            int row = row0 + half * 4 + e;
            xs[(half * 4 + e) * DIM + tc] = (row < NR) ? rel[(size_t)row * DIM + tc] : 0.0f;
        }
        __syncthreads();
        float acc[4] = {0.f, 0.f, 0.f, 0.f};
        #pragma unroll 4
        for (int k = 0; k < DIM; ++k) {
            const float wv = W_rel[k * DIM + tc];
            #pragma unroll
            for (int e = 0; e < 4; ++e) acc[e] += xs[(half * 4 + e) * DIM + k] * wv;
        }
        const float wa2 = Wa2[tc];
        const int lane = t & 63;
        #pragma unroll
        for (int e = 0; e < 4; ++e) {
            float v = acc[e] * wa2;
            #pragma unroll
            for (int o = 32; o > 0; o >>= 1) v += __shfl_down(v, o);
            if (lane == 0) sred[(half * 4 + e) * 2 + ((t >> 6) & 1)] = v;
        }
        __syncthreads();
        #pragma unroll
        for (int e = 0; e < 4; ++e) {
            int row = row0 + half * 4 + e;
            float hi = __shfl_down(acc[e], 1);
            if (row < NR && (tc & 1) == 0)
                P2h[(size_t)row * 64 + (tc >> 1)] = pack_bf16(acc[e], hi);
        }
        if (t < 8) {
            int row = row0 + t;
            if (row < NR) q2[row] = sred[t * 2] + sred[t * 2 + 1];
        }
        return;
    }
    b -= RB;

    // ---------------- ent MFMA projection path ----------------
    const int wave = t >> 6;
    const int tile2 = b * 4 + wave;
    const bool active = tile2 < NT2;
    const int lane = t & 63;
    const int g = lane >> 4;               // k-group / row-group
    const int m = lane & 15;               // A row in tile; C col in tile
    unsigned short* lds16 = (unsigned short*)smem + wave * 2080;  // 16 rows x 130
    unsigned* lds32 = smem + wave * 1040;                          // same, dword view
    int half = 0, row0 = 0;
    unsigned* Ph = P1h;
    if (active) {
        half = tile2 & 1;
        row0 = (tile2 >> 1) * 16;
        Ph = half ? P3h : P1h;
        float* qo = half ? q3 : q1;
        const unsigned short* Wh = Wt + half * 128 * DIM;

        const int rowA = min(row0 + m, NE - 1);
        const float* arow = ent + (size_t)rowA * DIM;
        bf16x8 afrag[4];
        #pragma unroll
        for (int kk = 0; kk < 4; ++kk) {
            const float4 u0 = *(const float4*)(arow + kk * 32 + g * 8);
            const float4 u1 = *(const float4*)(arow + kk * 32 + g * 8 + 4);
            bf16x8 a;
            a[0] = (short)to_bf16(u0.x); a[1] = (short)to_bf16(u0.y);
            a[2] = (short)to_bf16(u0.z); a[3] = (short)to_bf16(u0.w);
            a[4] = (short)to_bf16(u1.x); a[5] = (short)to_bf16(u1.y);
            a[6] = (short)to_bf16(u1.z); a[7] = (short)to_bf16(u1.w);
            afrag[kk] = a;
        }

        float qp[4] = {0.f, 0.f, 0.f, 0.f};
        #pragma unroll
        for (int ct = 0; ct < 8; ++ct) {
            f32x4 acc = {0.f, 0.f, 0.f, 0.f};
            #pragma unroll
            for (int kk = 0; kk < 4; ++kk) {
                const bf16x8 bb = *(const bf16x8*)(Wh + (ct * 16 + m) * DIM + kk * 32 + g * 8);
                acc = __builtin_amdgcn_mfma_f32_16x16x32_bf16(afrag[kk], bb, acc, 0, 0, 0);
            }
            const int c = ct * 16 + m;     // 0..127 output column
            const float bias = half ? 0.0f : b_a[c];
            const float wa2  = Wa2[c];
            #pragma unroll
            for (int r = 0; r < 4; ++r) {
                const float v = acc[r] + bias;
                qp[r] += v * wa2;
                lds16[(g * 4 + r) * 130 + c] = to_bf16(v);   // all 64 lanes, ~2-way banks
            }
        }

        // q reduce over the 16 lanes of each row-group
        #pragma unroll
        for (int r = 0; r < 4; ++r) {
            float v = qp[r];
            #pragma unroll
            for (int o = 1; o < 16; o <<= 1) v += __shfl_xor(v, o);
            const int row = row0 + g * 4 + r;
            if (m == 0 && row < NE) qo[row] = v;
        }
    }
    __syncthreads();
    if (active) {
        #pragma unroll
        for (int i = 0; i < 16; ++i) {
            const int row = row0 + i;
            if (row < NE) Ph[(size_t)row * 64 + lane] = lds32[i * 65 + lane];
        }
    }
}

// ---------------------------------------------------------------------------
__device__ inline int wave_incl_scan(int v) {
    const int lane = threadIdx.x & 63;
    #pragma unroll
    for (int o = 1; o < 64; o <<= 1) {
        int u = __shfl_up(v, o);
        if (lane >= o) v += u;
    }
    return v;
}

__global__ void scan_bsum_kernel(const int* __restrict__ counts, int* __restrict__ bsum, int n) {
    const int t = threadIdx.x;                 // 256
    const int base = blockIdx.x * 1024 + t * 4;
    int s = 0;
    #pragma unroll
    for (int j = 0; j < 4; ++j) if (base + j < n) s += counts[base + j];
    #pragma unroll
    for (int o = 32; o > 0; o >>= 1) s += __shfl_down(s, o);
    __shared__ int ws[4];
    if ((t & 63) == 0) ws[t >> 6] = s;
    __syncthreads();
    if (t == 0) bsum[blockIdx.x] = ws[0] + ws[1] + ws[2] + ws[3];
}

// scan_write with fused block-offset computation (reads bsum directly)
__global__ void scan_write_kernel(const int* __restrict__ counts, const int* __restrict__ bsum,
                                  int* __restrict__ offsets, int* __restrict__ cursor,
                                  int n, int total, int nb) {
    __shared__ int s_boff;
    __shared__ int wsum[4], wpre[4];
    const int t = threadIdx.x;                 // 256
    if (t < 64) {
        int v = (t < nb) ? bsum[t] : 0;
        int incl = wave_incl_scan(v);
        int ex = incl - v;
        int want = __shfl(ex, (int)blockIdx.x);
        if (t == 0) s_boff = want;
    }
    const int base = blockIdx.x * 1024 + t * 4;
    int c[4];
    int s = 0;
    #pragma unroll
    for (int j = 0; j < 4; ++j) {
        c[j] = (base + j < n) ? counts[base + j] : 0;
        s += c[j];
    }
    int incl = wave_incl_scan(s);
    const int wid = t >> 6, lane = t & 63;
    if (lane == 63) wsum[wid] = incl;
    __syncthreads();
    if (t == 0) {
        int run = 0;
        #pragma unroll
        for (int k = 0; k < 4; ++k) { wpre[k] = run; run += wsum[k]; }
    }
    __syncthreads();
    int run = incl - s + wpre[wid] + s_boff;
    #pragma unroll
    for (int j = 0; j < 4; ++j) {
        if (base + j < n) { offsets[base + j] = run; cursor[base + j] = run; run += c[j]; }
    }
    if (base == 0 && blockIdx.x == 0) offsets[n] = total;
}

// ---------------------------------------------------------------------------
// fused weight + scatter: w = exp(lrelu(q1[s]+q2[r]+q3[d]+b_a2));
// payload packed to 8 B: {(r<<17)|d, w}   (requires NR<2^15, NE<2^17)
// ---------------------------------------------------------------------------
__global__ void scatter_kernel(const int* __restrict__ T, const float* __restrict__ q1,
                               const float* __restrict__ q2, const float* __restrict__ q3,
                               const float* __restrict__ b_a2, int* __restrict__ cursor,
                               uint2* __restrict__ rdw, int E) {
    const int e = blockIdx.x * blockDim.x + threadIdx.x;
    if (e >= E) return;
    const int s = T[e], r = T[E + e], d = T[2 * E + e];
    float b = q1[s] + q2[r] + q3[d] + b_a2[0];
    b = (b > 0.0f) ? b : 0.01f * b;
    const float wv = __expf(b);
    const int pos = atomicAdd(&cursor[s], 1);
    rdw[pos] = make_uint2(((unsigned)r << 17) | (unsigned)d, __float_as_uint(wv));
}

// ---------------------------------------------------------------------------
// one wave per node, unrolled x4: gather bf16 rows, normalize, add P1b, elu.
// out is WRITE-ONLY (float2 per lane).
// ---------------------------------------------------------------------------
__global__ void gather_kernel(const int* __restrict__ offsets, const uint2* __restrict__ rdw,
                              const unsigned* __restrict__ P1h, const unsigned* __restrict__ P2h,
                              const unsigned* __restrict__ P3h, float* __restrict__ out, int n) {
    const int node = (blockIdx.x << 2) + (threadIdx.x >> 6);   // 4 waves/block
    if (node >= n) return;
    const int lane = threadIdx.x & 63;
    const int lo = offsets[node], hi = offsets[node + 1];
    float axp[4] = {0.f,0.f,0.f,0.f};
    float ayp[4] = {0.f,0.f,0.f,0.f};
    float wsp[4] = {0.f,0.f,0.f,0.f};
    int i = lo;
    for (; i + 3 < hi; i += 4) {
        uint2 e[4];
        #pragma unroll
        for (int j = 0; j < 4; ++j) e[j] = rdw[i + j];
        unsigned v2[4], v3[4];
        #pragma unroll
        for (int j = 0; j < 4; ++j) {
            v2[j] = P2h[(size_t)(e[j].x >> 17) * 64 + lane];
            v3[j] = P3h[(size_t)(e[j].x & 0x1FFFFu) * 64 + lane];
        }
        #pragma unroll
        for (int j = 0; j < 4; ++j) {
            const float wv = __uint_as_float(e[j].y);
            axp[j] += wv * (unpack_lo(v2[j]) + unpack_lo(v3[j]));
            ayp[j] += wv * (unpack_hi(v2[j]) + unpack_hi(v3[j]));
            wsp[j] += wv;
        }
    }
    for (; i < hi; ++i) {
        const uint2 e0 = rdw[i];
        const unsigned v2a = P2h[(size_t)(e0.x >> 17) * 64 + lane];
        const unsigned v3a = P3h[(size_t)(e0.x & 0x1FFFFu) * 64 + lane];
        const float wv = __uint_as_float(e0.y);
        axp[0] += wv * (unpack_lo(v2a) + unpack_lo(v3a));
        ayp[0] += wv * (unpack_hi(v2a) + unpack_hi(v3a));
        wsp[0] += wv;
    }
    const float ax = (axp[0] + axp[1]) + (axp[2] + axp[3]);
    const float ay = (ayp[0] + ayp[1]) + (ayp[2] + ayp[3]);
    const float inv = 1.0f / ((wsp[0] + wsp[1]) + (wsp[2] + wsp[3]));
    const unsigned p1 = P1h[(size_t)node * 64 + lane];
    float v0 = unpack_lo(p1) + ax * inv;
    float v1 = unpack_hi(p1) + ay * inv;
    v0 = (v0 > 0.0f) ? v0 : (__expf(v0) - 1.0f);
    v1 = (v1 > 0.0f) ? v1 : (__expf(v1) - 1.0f);
    *(float2*)(out + (size_t)node * DIM + (lane << 1)) = make_float2(v0, v1);
}

extern "C" void kernel_launch(void* const* d_in, const int* in_sizes, int n_in,
                              void* d_out, int out_size, void* d_ws, size_t ws_size,
                              hipStream_t stream) {
    const int*   T    = (const int*)d_in[0];
    const float* ent  = (const float*)d_in[1];
    const float* rel  = (const float*)d_in[2];
    const float* W_a  = (const float*)d_in[4];
    const float* b_a  = (const float*)d_in[5];
    const float* W_a2 = (const float*)d_in[6];
    const float* b_a2 = (const float*)d_in[7];
    float* out = (float*)d_out;

    const int E  = in_sizes[0] / 3;
    const int NE = in_sizes[1] / DIM;
    const int NR = in_sizes[2] / DIM;
    const int NB = (NE + 1023) / 1024;         // scan blocks (<=64 supported)
    const int NT2 = ((NE + 15) / 16) * 2;      // 16-row MFMA tiles x 2 halves
    const int HB = 256;                        // hist blocks (fused stage1)
    const int RB = (NR + 7) / 8;               // rel-proj blocks
    const int PB = (NT2 + 3) / 4;              // ent-proj blocks

    float* ws = (float*)d_ws;
    size_t off = 0;
    unsigned* P1h = (unsigned*)(ws + off); off += (size_t)NE * 64;
    unsigned* P3h = (unsigned*)(ws + off); off += (size_t)NE * 64;
    unsigned* P2h = (unsigned*)(ws + off); off += (size_t)NR * 64;
    unsigned short* Wt = (unsigned short*)(ws + off); off += 256 * DIM / 2;
    float* q1   = ws + off; off += NE;
    float* q3   = ws + off; off += NE;
    float* q2   = ws + off; off += NR + 64;
    int* counts  = (int*)(ws + off); off += NE;
    int* offsets = (int*)(ws + off); off += NE + 64;
    int* cursor  = (int*)(ws + off); off += NE;
    int* bsum    = (int*)(ws + off); off += 64;
    uint2* rdw   = (uint2*)(ws + off); off += (size_t)E * 2;

    // W transpose+bf16 pack for the MFMA B operand; also zero counts
    wprep_kernel<<<256, 128, 0, stream>>>(W_a, Wt, counts, NE);

    // fused stage 1: hist + rel projection + ent MFMA projection
    stage1_kernel<<<HB + RB + PB, 256, 0, stream>>>(
        ent, rel, T, Wt, W_a + 128 * DIM, b_a, W_a2,
        P1h, P3h, P2h, q1, q3, q2, counts, NE, NR, E, NT2, HB, RB);

    // hierarchical CSR scan (boff fused into scan_write)
    scan_bsum_kernel<<<NB, 256, 0, stream>>>(counts, bsum, NE);
    scan_write_kernel<<<NB, 256, 0, stream>>>(counts, bsum, offsets, cursor, NE, E, NB);

    // fused weight + scatter (8 B payload per edge)
    scatter_kernel<<<(E + 255) / 256, 256, 0, stream>>>(T, q1, q2, q3, b_a2, cursor, rdw, E);

    // gather + normalize + elu (write-only out, unrolled x4)
    gather_kernel<<<(NE + 3) / 4, 256, 0, stream>>>(offsets, rdw, P1h, P2h, P3h, out, NE);
}

// Round 9
// 111.769 us; speedup vs baseline: 5.1684x; 1.0970x over previous
//
#include <hip/hip_runtime.h>

#define DIM 128

typedef __attribute__((ext_vector_type(8))) short bf16x8;
typedef __attribute__((ext_vector_type(4))) float f32x4;

// ---- bf16 helpers (RNE) ----------------------------------------------------
__device__ inline unsigned short to_bf16(float f) {
    unsigned u = __float_as_uint(f);
    u = (u + 0x7FFFu + ((u >> 16) & 1u)) >> 16;
    return (unsigned short)u;
}
__device__ inline unsigned pack_bf16(float lo, float hi) {
    return (unsigned)to_bf16(lo) | ((unsigned)to_bf16(hi) << 16);
}
__device__ inline float unpack_lo(unsigned v) { return __uint_as_float(v << 16); }
__device__ inline float unpack_hi(unsigned v) { return __uint_as_float(v & 0xFFFF0000u); }

// ---------------------------------------------------------------------------
// W prep: Wt[c][k] (bf16, c in 0..255) = W_a[k][c] (c<128) | W_a[256+k][c-128]
// Also zeroes the histogram.
// ---------------------------------------------------------------------------
__global__ void wprep_kernel(const float* __restrict__ W_a, unsigned short* __restrict__ Wt,
                             int* __restrict__ counts, int n) {
    const int c = blockIdx.x;          // 0..255
    const int k = threadIdx.x;         // 0..127
    const int srow = (c < 128) ? k : (256 + k);
    const int scol = (c < 128) ? c : (c - 128);
    Wt[c * DIM + k] = to_bf16(W_a[srow * DIM + scol]);
    for (int i = blockIdx.x * 128 + k; i < n; i += 256 * 128) counts[i] = 0;
}

// ---------------------------------------------------------------------------
// Fused stage 1, block roles (GEMM first = longest pole):
//  [0, GB)        : ent MFMA GEMM, 128 rows x 128 cols (half=b&1 -> W1|W3)
//  [GB, GB+HB)    : histogram counts[src]++
//  [GB+HB, +RB)   : rel projection -> P2h + q2
// GEMM: A staged once per block in LDS (bf16, XOR-swizzled), B streamed from
// L2 (Wt), A-frags hoisted per kk; 64 MFMA / wave; epilogue restages output
// in LDS for fully-coalesced stores; q-dots fused.
// ---------------------------------------------------------------------------
__global__ __launch_bounds__(256, 4) void stage1_kernel(
        const float* __restrict__ ent, const float* __restrict__ rel,
        const int* __restrict__ T, const unsigned short* __restrict__ Wt,
        const float* __restrict__ W_rel, const float* __restrict__ b_a,
        const float* __restrict__ Wa2,
        unsigned* __restrict__ P1h, unsigned* __restrict__ P3h, unsigned* __restrict__ P2h,
        float* __restrict__ q1, float* __restrict__ q3, float* __restrict__ q2,
        int* __restrict__ counts, int NE, int NR, int E, int GB, int HB, int RB) {
    __shared__ unsigned smem[8320];    // 33.3 KB: A-tile (8192 dw) / out-stage (128x65 dw)
    int b = blockIdx.x;
    const int t = threadIdx.x;

    // ---------------- ent GEMM role ----------------
    if (b < GB) {
        const int half = b & 1;
        const int mrow = (b >> 1) * 128;

        // stage A: 128 rows x 128 cols fp32 -> bf16 LDS, XOR-swizzled rows
        #pragma unroll 4
        for (int i = 0; i < 16; ++i) {
            const int idx = i * 256 + t;           // float4 index (4096 total)
            const int row = idx >> 5;              // 0..127
            const int f4  = idx & 31;              // 0..31
            const int rg  = min(mrow + row, NE - 1);
            const float4 u = *(const float4*)(ent + (size_t)rg * DIM + f4 * 4);
            const unsigned d0 = pack_bf16(u.x, u.y);
            const unsigned d1 = pack_bf16(u.z, u.w);
            const int dw = (f4 * 2) ^ ((row & 7) << 2);
            *(uint2*)&smem[row * 64 + dw] = make_uint2(d0, d1);
        }
        __syncthreads();

        const int wv = t >> 6, lane = t & 63;
        const int g = lane >> 4, m = lane & 15;
        const unsigned short* Wh = Wt + half * 128 * DIM;

        f32x4 acc[2][8];
        #pragma unroll
        for (int rt = 0; rt < 2; ++rt)
            #pragma unroll
            for (int ct = 0; ct < 8; ++ct) acc[rt][ct] = (f32x4){0.f, 0.f, 0.f, 0.f};

        #pragma unroll
        for (int kk = 0; kk < 4; ++kk) {
            const int dwa = (kk * 16 + g * 4) ^ ((m & 7) << 2);
            const bf16x8 a0 = *(const bf16x8*)&smem[(wv * 32 + m) * 64 + dwa];
            const bf16x8 a1 = *(const bf16x8*)&smem[(wv * 32 + 16 + m) * 64 + dwa];
            #pragma unroll
            for (int ct = 0; ct < 8; ++ct) {
                const bf16x8 bb = *(const bf16x8*)(Wh + (ct * 16 + m) * DIM + kk * 32 + g * 8);
                acc[0][ct] = __builtin_amdgcn_mfma_f32_16x16x32_bf16(a0, bb, acc[0][ct], 0, 0, 0);
                acc[1][ct] = __builtin_amdgcn_mfma_f32_16x16x32_bf16(a1, bb, acc[1][ct], 0, 0, 0);
            }
        }
        __syncthreads();   // A-tile dead; reuse smem for output staging

        unsigned* __restrict__ Ph = half ? P3h : P1h;
        float*    __restrict__ qo = half ? q3  : q1;
        unsigned short* lds16 = (unsigned short*)smem;   // [128][130]

        #pragma unroll
        for (int rt = 0; rt < 2; ++rt) {
            float qp[4] = {0.f, 0.f, 0.f, 0.f};
            #pragma unroll
            for (int ct = 0; ct < 8; ++ct) {
                const int c = ct * 16 + m;
                const float bias = half ? 0.0f : b_a[c];
                const float wa2  = Wa2[c];
                #pragma unroll
                for (int r = 0; r < 4; ++r) {
                    const float v = acc[rt][ct][r] + bias;
                    qp[r] += v * wa2;
                    lds16[(wv * 32 + rt * 16 + g * 4 + r) * 130 + c] = to_bf16(v);
                }
            }
            #pragma unroll
            for (int r = 0; r < 4; ++r) {
                float v = qp[r];
                #pragma unroll
                for (int o = 1; o < 16; o <<= 1) v += __shfl_xor(v, o);
                const int row = mrow + wv * 32 + rt * 16 + g * 4 + r;
                if (m == 0 && row < NE) qo[row] = v;
            }
        }
        __syncthreads();
        // coalesced copy-out: 128 rows x 64 dwords
        for (int i = 0; i < 32; ++i) {
            const int linear = i * 256 + t;
            const int row = linear >> 6, d = linear & 63;
            const int rg = mrow + row;
            if (rg < NE) Ph[(size_t)rg * 64 + d] = smem[row * 65 + d];
        }
        return;
    }
    b -= GB;

    // ---------------- histogram role ----------------
    if (b < HB) {
        for (int e = b * 256 + t; e < E; e += HB * 256)
            atomicAdd(&counts[T[e]], 1);
        return;
    }
    b -= HB;

    // ---------------- rel projection role ----------------
    {
        float* xs   = (float*)smem;            // [8][DIM]
        float* sred = (float*)(smem + 1024);   // [8][2]
        const int row0 = b * 8;
        const int half = t >> 7;               // 0..1 (4 rows each)
        const int tc   = t & 127;              // column
        #pragma unroll
        for (int e = 0; e < 4; ++e) {
            int row = row0 + half * 4 + e;
            xs[(half * 4 + e) * DIM + tc] = (row < NR) ? rel[(size_t)row * DIM + tc] : 0.0f;
        }
        __syncthreads();
        float acc[4] = {0.f, 0.f, 0.f, 0.f};
        #pragma unroll 4
        for (int k = 0; k < DIM; ++k) {
            const float wv = W_rel[k * DIM + tc];
            #pragma unroll
            for (int e = 0; e < 4; ++e) acc[e] += xs[(half * 4 + e) * DIM + k] * wv;
        }
        const float wa2 = Wa2[tc];
        const int lane = t & 63;
        #pragma unroll
        for (int e = 0; e < 4; ++e) {
            float v = acc[e] * wa2;
            #pragma unroll
            for (int o = 32; o > 0; o >>= 1) v += __shfl_down(v, o);
            if (lane == 0) sred[(half * 4 + e) * 2 + ((t >> 6) & 1)] = v;
        }
        __syncthreads();
        #pragma unroll
        for (int e = 0; e < 4; ++e) {
            int row = row0 + half * 4 + e;
            float hi = __shfl_down(acc[e], 1);
            if (row < NR && (tc & 1) == 0)
                P2h[(size_t)row * 64 + (tc >> 1)] = pack_bf16(acc[e], hi);
        }
        if (t < 8) {
            int row = row0 + t;
            if (row < NR) q2[row] = sred[t * 2] + sred[t * 2 + 1];
        }
    }
}

// ---------------------------------------------------------------------------
__device__ inline int wave_incl_scan(int v) {
    const int lane = threadIdx.x & 63;
    #pragma unroll
    for (int o = 1; o < 64; o <<= 1) {
        int u = __shfl_up(v, o);
        if (lane >= o) v += u;
    }
    return v;
}

__global__ void scan_bsum_kernel(const int* __restrict__ counts, int* __restrict__ bsum, int n) {
    const int t = threadIdx.x;                 // 256
    const int base = blockIdx.x * 1024 + t * 4;
    int s = 0;
    #pragma unroll
    for (int j = 0; j < 4; ++j) if (base + j < n) s += counts[base + j];
    #pragma unroll
    for (int o = 32; o > 0; o >>= 1) s += __shfl_down(s, o);
    __shared__ int ws[4];
    if ((t & 63) == 0) ws[t >> 6] = s;
    __syncthreads();
    if (t == 0) bsum[blockIdx.x] = ws[0] + ws[1] + ws[2] + ws[3];
}

__global__ void scan_write_kernel(const int* __restrict__ counts, const int* __restrict__ bsum,
                                  int* __restrict__ offsets, int* __restrict__ cursor,
                                  int n, int total, int nb) {
    __shared__ int s_boff;
    __shared__ int wsum[4], wpre[4];
    const int t = threadIdx.x;                 // 256
    if (t < 64) {
        int v = (t < nb) ? bsum[t] : 0;
        int incl = wave_incl_scan(v);
        int ex = incl - v;
        int want = __shfl(ex, (int)blockIdx.x);
        if (t == 0) s_boff = want;
    }
    const int base = blockIdx.x * 1024 + t * 4;
    int c[4];
    int s = 0;
    #pragma unroll
    for (int j = 0; j < 4; ++j) {
        c[j] = (base + j < n) ? counts[base + j] : 0;
        s += c[j];
    }
    int incl = wave_incl_scan(s);
    const int wid = t >> 6, lane = t & 63;
    if (lane == 63) wsum[wid] = incl;
    __syncthreads();
    if (t == 0) {
        int run = 0;
        #pragma unroll
        for (int k = 0; k < 4; ++k) { wpre[k] = run; run += wsum[k]; }
    }
    __syncthreads();
    int run = incl - s + wpre[wid] + s_boff;
    #pragma unroll
    for (int j = 0; j < 4; ++j) {
        if (base + j < n) { offsets[base + j] = run; cursor[base + j] = run; run += c[j]; }
    }
    if (base == 0 && blockIdx.x == 0) offsets[n] = total;
}

// ---------------------------------------------------------------------------
// fused weight + scatter: w = exp(lrelu(q1[s]+q2[r]+q3[d]+b_a2));
// payload 8 B: {(r<<17)|d, w}   (requires NR<2^15, NE<2^17)
// ---------------------------------------------------------------------------
__global__ void scatter_kernel(const int* __restrict__ T, const float* __restrict__ q1,
                               const float* __restrict__ q2, const float* __restrict__ q3,
                               const float* __restrict__ b_a2, int* __restrict__ cursor,
                               uint2* __restrict__ rdw, int E) {
    const int e = blockIdx.x * blockDim.x + threadIdx.x;
    if (e >= E) return;
    const int s = T[e], r = T[E + e], d = T[2 * E + e];
    float b = q1[s] + q2[r] + q3[d] + b_a2[0];
    b = (b > 0.0f) ? b : 0.01f * b;
    const float wv = __expf(b);
    const int pos = atomicAdd(&cursor[s], 1);
    rdw[pos] = make_uint2(((unsigned)r << 17) | (unsigned)d, __float_as_uint(wv));
}

// ---------------------------------------------------------------------------
// one wave per node, unrolled x4: gather bf16 rows, normalize, add P1b, elu.
// ---------------------------------------------------------------------------
__global__ void gather_kernel(const int* __restrict__ offsets, const uint2* __restrict__ rdw,
                              const unsigned* __restrict__ P1h, const unsigned* __restrict__ P2h,
                              const unsigned* __restrict__ P3h, float* __restrict__ out, int n) {
    const int node = (blockIdx.x << 2) + (threadIdx.x >> 6);   // 4 waves/block
    if (node >= n) return;
    const int lane = threadIdx.x & 63;
    const int lo = offsets[node], hi = offsets[node + 1];
    float axp[4] = {0.f,0.f,0.f,0.f};
    float ayp[4] = {0.f,0.f,0.f,0.f};
    float wsp[4] = {0.f,0.f,0.f,0.f};
    int i = lo;
    for (; i + 3 < hi; i += 4) {
        uint2 e[4];
        #pragma unroll
        for (int j = 0; j < 4; ++j) e[j] = rdw[i + j];
        unsigned v2[4], v3[4];
        #pragma unroll
        for (int j = 0; j < 4; ++j) {
            v2[j] = P2h[(size_t)(e[j].x >> 17) * 64 + lane];
            v3[j] = P3h[(size_t)(e[j].x & 0x1FFFFu) * 64 + lane];
        }
        #pragma unroll
        for (int j = 0; j < 4; ++j) {
            const float wv = __uint_as_float(e[j].y);
            axp[j] += wv * (unpack_lo(v2[j]) + unpack_lo(v3[j]));
            ayp[j] += wv * (unpack_hi(v2[j]) + unpack_hi(v3[j]));
            wsp[j] += wv;
        }
    }
    for (; i < hi; ++i) {
        const uint2 e0 = rdw[i];
        const unsigned v2a = P2h[(size_t)(e0.x >> 17) * 64 + lane];
        const unsigned v3a = P3h[(size_t)(e0.x & 0x1FFFFu) * 64 + lane];
        const float wv = __uint_as_float(e0.y);
        axp[0] += wv * (unpack_lo(v2a) + unpack_lo(v3a));
        ayp[0] += wv * (unpack_hi(v2a) + unpack_hi(v3a));
        wsp[0] += wv;
    }
    const float ax = (axp[0] + axp[1]) + (axp[2] + axp[3]);
    const float ay = (ayp[0] + ayp[1]) + (ayp[2] + ayp[3]);
    const float inv = 1.0f / ((wsp[0] + wsp[1]) + (wsp[2] + wsp[3]));
    const unsigned p1 = P1h[(size_t)node * 64 + lane];
    float v0 = unpack_lo(p1) + ax * inv;
    float v1 = unpack_hi(p1) + ay * inv;
    v0 = (v0 > 0.0f) ? v0 : (__expf(v0) - 1.0f);
    v1 = (v1 > 0.0f) ? v1 : (__expf(v1) - 1.0f);
    *(float2*)(out + (size_t)node * DIM + (lane << 1)) = make_float2(v0, v1);
}

extern "C" void kernel_launch(void* const* d_in, const int* in_sizes, int n_in,
                              void* d_out, int out_size, void* d_ws, size_t ws_size,
                              hipStream_t stream) {
    const int*   T    = (const int*)d_in[0];
    const float* ent  = (const float*)d_in[1];
    const float* rel  = (const float*)d_in[2];
    const float* W_a  = (const float*)d_in[4];
    const float* b_a  = (const float*)d_in[5];
    const float* W_a2 = (const float*)d_in[6];
    const float* b_a2 = (const float*)d_in[7];
    float* out = (float*)d_out;

    const int E  = in_sizes[0] / 3;
    const int NE = in_sizes[1] / DIM;
    const int NR = in_sizes[2] / DIM;
    const int NB = (NE + 1023) / 1024;         // scan blocks (<=64 supported)
    const int GB = ((NE + 127) / 128) * 2;     // GEMM blocks (128 rows x 2 halves)
    const int HB = 256;                        // hist blocks
    const int RB = (NR + 7) / 8;               // rel-proj blocks

    float* ws = (float*)d_ws;
    size_t off = 0;
    unsigned* P1h = (unsigned*)(ws + off); off += (size_t)NE * 64;
    unsigned* P3h = (unsigned*)(ws + off); off += (size_t)NE * 64;
    unsigned* P2h = (unsigned*)(ws + off); off += (size_t)NR * 64;
    unsigned short* Wt = (unsigned short*)(ws + off); off += 256 * DIM / 2;
    float* q1   = ws + off; off += NE;
    float* q3   = ws + off; off += NE;
    float* q2   = ws + off; off += NR + 64;
    int* counts  = (int*)(ws + off); off += NE;
    int* offsets = (int*)(ws + off); off += NE + 64;
    int* cursor  = (int*)(ws + off); off += NE;
    int* bsum    = (int*)(ws + off); off += 64;
    uint2* rdw   = (uint2*)(ws + off); off += (size_t)E * 2;

    // W transpose+bf16 pack for the MFMA B operand; also zero counts
    wprep_kernel<<<256, 128, 0, stream>>>(W_a, Wt, counts, NE);

    // fused stage 1: ent GEMM + hist + rel projection
    stage1_kernel<<<GB + HB + RB, 256, 0, stream>>>(
        ent, rel, T, Wt, W_a + 128 * DIM, b_a, W_a2,
        P1h, P3h, P2h, q1, q3, q2, counts, NE, NR, E, GB, HB, RB);

    // hierarchical CSR scan
    scan_bsum_kernel<<<NB, 256, 0, stream>>>(counts, bsum, NE);
    scan_write_kernel<<<NB, 256, 0, stream>>>(counts, bsum, offsets, cursor, NE, E, NB);

    // fused weight + scatter (8 B payload per edge)
    scatter_kernel<<<(E + 255) / 256, 256, 0, stream>>>(T, q1, q2, q3, b_a2, cursor, rdw, E);

    // gather + normalize + elu (write-only out, unrolled x4)
    gather_kernel<<<(NE + 3) / 4, 256, 0, stream>>>(offsets, rdw, P1h, P2h, P3h, out, NE);
}